// Round 1
// baseline (1437.422 us; speedup 1.0000x reference)
//
#include <hip/hip_runtime.h>
#include <hip/hip_bf16.h>
#include <math.h>

// Problem constants
#define Bb 8
#define Nn 2048
#define Mm 2048
#define Cc 512

// Tile config: 128x128 tile, K-tile 8, 256 threads, 8x8 micro-tile per thread.
#define TBM 128
#define TBN 128
#define TBK 8
#define TPAD 4  // keeps each LDS row 16B-aligned (132 floats = 528 B)

// ---------------------------------------------------------------------------
// NT GEMM with mask epilogue: S[n,m] = (sum_k dec[n,k]*enc[m,k]) * mask[n,m]
// ---------------------------------------------------------------------------
__global__ __launch_bounds__(256) void score_kernel(
    const float* __restrict__ dec, const float* __restrict__ enc,
    const float* __restrict__ mask, float* __restrict__ S)
{
    const int b = blockIdx.z;
    const float* A  = dec + (size_t)b * Nn * Cc;
    const float* Bp = enc + (size_t)b * Mm * Cc;
    const float* Mk = mask + (size_t)b * Nn * Mm;
    float* C = S + (size_t)b * Nn * Mm;

    __shared__ float As[TBK][TBM + TPAD];
    __shared__ float Bs[TBK][TBN + TPAD];

    const int tid = threadIdx.x;
    const int tx = tid & 15;
    const int ty = tid >> 4;
    const int lrow = tid >> 1;        // 0..127
    const int lkv  = (tid & 1) * 4;   // 0 or 4

    const int rowBase = blockIdx.y * TBM;
    const int colBase = blockIdx.x * TBN;

    float acc[8][8] = {};

    for (int k0 = 0; k0 < Cc; k0 += TBK) {
        float4 av = *(const float4*)(A  + (size_t)(rowBase + lrow) * Cc + k0 + lkv);
        float4 bv = *(const float4*)(Bp + (size_t)(colBase + lrow) * Cc + k0 + lkv);
        As[lkv+0][lrow] = av.x; As[lkv+1][lrow] = av.y;
        As[lkv+2][lrow] = av.z; As[lkv+3][lrow] = av.w;
        Bs[lkv+0][lrow] = bv.x; Bs[lkv+1][lrow] = bv.y;
        Bs[lkv+2][lrow] = bv.z; Bs[lkv+3][lrow] = bv.w;
        __syncthreads();
        #pragma unroll
        for (int k = 0; k < TBK; ++k) {
            float4 a0 = *(const float4*)&As[k][ty*8];
            float4 a1 = *(const float4*)&As[k][ty*8+4];
            float4 b0 = *(const float4*)&Bs[k][tx*8];
            float4 b1 = *(const float4*)&Bs[k][tx*8+4];
            float aa[8] = {a0.x,a0.y,a0.z,a0.w,a1.x,a1.y,a1.z,a1.w};
            float bb[8] = {b0.x,b0.y,b0.z,b0.w,b1.x,b1.y,b1.z,b1.w};
            #pragma unroll
            for (int i = 0; i < 8; ++i)
                #pragma unroll
                for (int j = 0; j < 8; ++j)
                    acc[i][j] = fmaf(aa[i], bb[j], acc[i][j]);
        }
        __syncthreads();
    }

    #pragma unroll
    for (int i = 0; i < 8; ++i) {
        const size_t row = rowBase + ty*8 + i;
        #pragma unroll
        for (int jv = 0; jv < 2; ++jv) {
            const size_t col = colBase + tx*8 + jv*4;
            float4 mk = *(const float4*)(Mk + row * Mm + col);
            float4 o;
            o.x = acc[i][jv*4+0] * mk.x;
            o.y = acc[i][jv*4+1] * mk.y;
            o.z = acc[i][jv*4+2] * mk.z;
            o.w = acc[i][jv*4+3] * mk.w;
            *(float4*)(C + row * Mm + col) = o;
        }
    }
}

// ---------------------------------------------------------------------------
// NN GEMM: C = epilogue(A @ W).  A [rows,K] row-major, W [K,Ncols] row-major.
// EPI 0: +bias; EPI 1: relu(+bias); EPI 2: gate*(1+tanh(acc)) (tanh-gate+res)
// Batched via blockIdx.z with strides sA/sW/sC (gate shares sC).
// ---------------------------------------------------------------------------
template<int EPI>
__global__ __launch_bounds__(256) void gemm_nn(
    const float* __restrict__ Ab, const float* __restrict__ Wb,
    const float* __restrict__ bias, const float* __restrict__ gate,
    float* __restrict__ Cb, int K, int Ncols,
    long sA, long sW, long sC)
{
    const int b = blockIdx.z;
    const float* A = Ab + (size_t)b * sA;
    const float* W = Wb + (size_t)b * sW;
    const float* G = gate + (size_t)b * sC;  // only dereferenced when EPI==2
    float* C = Cb + (size_t)b * sC;

    __shared__ float As[TBK][TBM + TPAD];
    __shared__ float Bs[TBK][TBN + TPAD];

    const int tid = threadIdx.x;
    const int tx = tid & 15;
    const int ty = tid >> 4;
    const int lrow = tid >> 1;        // 0..127
    const int lkv  = (tid & 1) * 4;   // 0 or 4
    const int wr   = tid >> 5;        // 0..7  (k row of W tile)
    const int wc   = (tid & 31) * 4;  // 0..124

    const int rowBase = blockIdx.y * TBM;
    const int colBase = blockIdx.x * TBN;

    float acc[8][8] = {};

    for (int k0 = 0; k0 < K; k0 += TBK) {
        float4 av = *(const float4*)(A + (size_t)(rowBase + lrow) * K + k0 + lkv);
        float4 wv = *(const float4*)(W + (size_t)(k0 + wr) * Ncols + colBase + wc);
        As[lkv+0][lrow] = av.x; As[lkv+1][lrow] = av.y;
        As[lkv+2][lrow] = av.z; As[lkv+3][lrow] = av.w;
        *(float4*)&Bs[wr][wc] = wv;
        __syncthreads();
        #pragma unroll
        for (int k = 0; k < TBK; ++k) {
            float4 a0 = *(const float4*)&As[k][ty*8];
            float4 a1 = *(const float4*)&As[k][ty*8+4];
            float4 b0 = *(const float4*)&Bs[k][tx*8];
            float4 b1 = *(const float4*)&Bs[k][tx*8+4];
            float aa[8] = {a0.x,a0.y,a0.z,a0.w,a1.x,a1.y,a1.z,a1.w};
            float bb[8] = {b0.x,b0.y,b0.z,b0.w,b1.x,b1.y,b1.z,b1.w};
            #pragma unroll
            for (int i = 0; i < 8; ++i)
                #pragma unroll
                for (int j = 0; j < 8; ++j)
                    acc[i][j] = fmaf(aa[i], bb[j], acc[i][j]);
        }
        __syncthreads();
    }

    #pragma unroll
    for (int i = 0; i < 8; ++i) {
        const size_t row = rowBase + ty*8 + i;
        #pragma unroll
        for (int jv = 0; jv < 2; ++jv) {
            const size_t col = colBase + tx*8 + jv*4;
            float4 o;
            o.x = acc[i][jv*4+0]; o.y = acc[i][jv*4+1];
            o.z = acc[i][jv*4+2]; o.w = acc[i][jv*4+3];
            if (EPI == 0 || EPI == 1) {
                float4 bi = *(const float4*)(bias + col);
                o.x += bi.x; o.y += bi.y; o.z += bi.z; o.w += bi.w;
                if (EPI == 1) {
                    o.x = fmaxf(o.x, 0.f); o.y = fmaxf(o.y, 0.f);
                    o.z = fmaxf(o.z, 0.f); o.w = fmaxf(o.w, 0.f);
                }
            } else {  // EPI == 2: g = gate*(1+tanh(acc))
                float4 gv = *(const float4*)(G + row * Ncols + col);
                o.x = gv.x * (1.f + tanhf(o.x));
                o.y = gv.y * (1.f + tanhf(o.y));
                o.z = gv.z * (1.f + tanhf(o.z));
                o.w = gv.w * (1.f + tanhf(o.w));
            }
            *(float4*)(C + row * Ncols + col) = o;
        }
    }
}

// ---------------------------------------------------------------------------
// Nonstandard masked softmax, in place. One block per row (M=2048, 256 thr).
// denom includes exp(0 - max) for masked (==0) entries; masked entries are
// then re-zeroed on output — exactly the reference semantics.
// ---------------------------------------------------------------------------
__global__ __launch_bounds__(256) void softmax_kernel(float* __restrict__ S)
{
    float* p = S + (size_t)blockIdx.x * Mm;
    const int tid = threadIdx.x;
    const int wv = tid >> 6, ln = tid & 63;

    float4 a = *(const float4*)(p + tid * 4);
    float4 c = *(const float4*)(p + 1024 + tid * 4);

    float mx = fmaxf(fmaxf(fmaxf(a.x, a.y), fmaxf(a.z, a.w)),
                     fmaxf(fmaxf(c.x, c.y), fmaxf(c.z, c.w)));
    #pragma unroll
    for (int off = 32; off >= 1; off >>= 1)
        mx = fmaxf(mx, __shfl_xor(mx, off, 64));

    __shared__ float sm[4], ss[4];
    if (ln == 0) sm[wv] = mx;
    __syncthreads();
    mx = fmaxf(fmaxf(sm[0], sm[1]), fmaxf(sm[2], sm[3]));

    float e[8];
    e[0] = __expf(a.x - mx); e[1] = __expf(a.y - mx);
    e[2] = __expf(a.z - mx); e[3] = __expf(a.w - mx);
    e[4] = __expf(c.x - mx); e[5] = __expf(c.y - mx);
    e[6] = __expf(c.z - mx); e[7] = __expf(c.w - mx);
    float s = e[0]+e[1]+e[2]+e[3]+e[4]+e[5]+e[6]+e[7];
    #pragma unroll
    for (int off = 32; off >= 1; off >>= 1)
        s += __shfl_xor(s, off, 64);
    if (ln == 0) ss[wv] = s;
    __syncthreads();
    s = ss[0] + ss[1] + ss[2] + ss[3];

    const float inv = 1.0f / s;
    float4 o1, o2;
    o1.x = (a.x == 0.f) ? 0.f : e[0] * inv;
    o1.y = (a.y == 0.f) ? 0.f : e[1] * inv;
    o1.z = (a.z == 0.f) ? 0.f : e[2] * inv;
    o1.w = (a.w == 0.f) ? 0.f : e[3] * inv;
    o2.x = (c.x == 0.f) ? 0.f : e[4] * inv;
    o2.y = (c.y == 0.f) ? 0.f : e[5] * inv;
    o2.z = (c.z == 0.f) ? 0.f : e[6] * inv;
    o2.w = (c.w == 0.f) ? 0.f : e[7] * inv;
    *(float4*)(p + tid * 4) = o1;
    *(float4*)(p + 1024 + tid * 4) = o2;
}

// ---------------------------------------------------------------------------
extern "C" void kernel_launch(void* const* d_in, const int* in_sizes, int n_in,
                              void* d_out, int out_size, void* d_ws, size_t ws_size,
                              hipStream_t stream)
{
    const float* dec   = (const float*)d_in[0];
    const float* enc   = (const float*)d_in[1];
    const float* trans = (const float*)d_in[2];
    const float* Wv = (const float*)d_in[3];
    const float* bv = (const float*)d_in[4];
    const float* W1 = (const float*)d_in[5];
    const float* b1 = (const float*)d_in[6];
    const float* W2 = (const float*)d_in[7];
    const float* b2 = (const float*)d_in[8];
    float* out = (float*)d_out;

    // ws layout: S [8*2048*2048] fp32 (134.2 MB) | vbuf [8*2048*512] (33.5 MB)
    // vbuf is reused for h after P@V. g is staged in d_out (dead before fc2).
    float* S    = (float*)d_ws;
    float* vbuf = S + (size_t)Bb * Nn * Mm;
    float* g    = out;
    float* h    = vbuf;

    // 1. vbuf = enc @ Wv + bv          [B*M, C]
    gemm_nn<0><<<dim3(Cc/TBN, (Bb*Mm)/TBM, 1), 256, 0, stream>>>(
        enc, Wv, bv, enc /*unused*/, vbuf, Cc, Cc, 0, 0, 0);

    // 2. S = (dec @ enc^T) * mask      [B, N, M]
    score_kernel<<<dim3(Mm/TBN, Nn/TBM, Bb), 256, 0, stream>>>(dec, enc, trans, S);

    // 3. masked softmax in place
    softmax_kernel<<<dim3(Bb*Nn), 256, 0, stream>>>(S);

    // 4. g = dec * (1 + tanh(P @ vbuf))   [B, N, C]  (batched)
    gemm_nn<2><<<dim3(Cc/TBN, Nn/TBM, Bb), 256, 0, stream>>>(
        S, vbuf, nullptr, dec, g, Mm, Cc,
        (long)Nn * Mm, (long)Mm * Cc, (long)Nn * Cc);

    // 5. h = relu(g @ W1 + b1)  (h overwrites vbuf, dead now)
    gemm_nn<1><<<dim3(Cc/TBN, (Bb*Nn)/TBM, 1), 256, 0, stream>>>(
        g, W1, b1, g /*unused*/, h, Cc, Cc, 0, 0, 0);

    // 6. out = h @ W2 + b2
    gemm_nn<0><<<dim3(Cc/TBN, (Bb*Nn)/TBM, 1), 256, 0, stream>>>(
        h, W2, b2, h /*unused*/, out, Cc, Cc, 0, 0, 0);
}

// Round 3
// 642.243 us; speedup vs baseline: 2.2381x; 2.2381x over previous
//
#include <hip/hip_runtime.h>
#include <math.h>

#define Bb 8
#define Nn 2048
#define Mm 2048
#define Cc 512

typedef __attribute__((ext_vector_type(8))) short bfrag;   // 8 bf16 = 4 VGPRs
typedef __attribute__((ext_vector_type(4))) float f4;      // MFMA acc
typedef __attribute__((ext_vector_type(4))) short s4v;

__device__ __forceinline__ unsigned short f2bf(float f) {
    unsigned u = __float_as_uint(f);
    u += 0x7fff + ((u >> 16) & 1);          // RNE
    return (unsigned short)(u >> 16);
}
__device__ __forceinline__ float bf2f(unsigned short s) {
    return __uint_as_float(((unsigned)s) << 16);
}

__device__ __forceinline__ void gld16(const void* g, void* l) {
    __builtin_amdgcn_global_load_lds(
        (const __attribute__((address_space(1))) void*)g,
        (__attribute__((address_space(3))) void*)l, 16, 0, 0);
}

// ---------------------------------------------------------------------------
// MFMA GEMM, 128x128 tile, BK=32, 4 waves each 64x64 (4x4 of 16x16x32 bf16).
// A [rows,K] bf16 row-major (lda elems, k contiguous).
// Bt [cols,K] bf16 row-major (ldb elems, k contiguous)  == B pre-transposed.
// SPLIT: A=Ah+Al, B=Bh+Bl, acc = ah*bh + ah*bl + al*bh  (fp32-like scores).
// EPI: 0=score (*mask, fp32 out)  1=vT (bias, bf16 transposed out)
//      2=gate (dec*(1+tanh), bf16 out)  3=relu+bias bf16  4=bias fp32 out
// ---------------------------------------------------------------------------
template<int EPI, bool SPLIT>
__global__ __launch_bounds__(256) void gemm_mfma(
    const short* __restrict__ Ah, const short* __restrict__ Al, long sA, int lda,
    const short* __restrict__ Bh, const short* __restrict__ Bl, long sB, int ldb,
    const float* __restrict__ aux, long sAux, int ldaux,
    void* __restrict__ Cout, long sC, int ldc, int K)
{
    __shared__ short As[128 * 32];
    __shared__ short Bs[128 * 32];
    __shared__ short As2[SPLIT ? 128 * 32 : 2];
    __shared__ short Bs2[SPLIT ? 128 * 32 : 2];

    const int b = blockIdx.z;
    const short* A0 = Ah + (size_t)b * sA;
    const short* B0 = Bh + (size_t)b * sB;
    const short* A1 = SPLIT ? (Al + (size_t)b * sA) : (const short*)nullptr;
    const short* B1 = SPLIT ? (Bl + (size_t)b * sB) : (const short*)nullptr;

    const int tid  = threadIdx.x;
    const int wv   = tid >> 6;
    const int ln   = tid & 63;
    const int wx   = wv & 1, wy = wv >> 1;
    const int lcol = ln & 15, quad = ln >> 4;

    const int rowBase = blockIdx.y * 128;
    const int colBase = blockIdx.x * 128;

    f4 acc[4][4];
    const f4 z4 = {0.f, 0.f, 0.f, 0.f};
    #pragma unroll
    for (int i = 0; i < 4; ++i)
        #pragma unroll
        for (int j = 0; j < 4; ++j) acc[i][j] = z4;

    for (int k0 = 0; k0 < K; k0 += 32) {
        __syncthreads();
        #pragma unroll
        for (int q = 0; q < 2; ++q) {
            const int c  = (wv * 2 + q) * 64 + ln;   // 16B chunk id, 512 total
            const int r  = c >> 2;                   // tile row 0..127
            const int ko = (c & 3) * 8;              // k offset in elems
            const int lb = (wv * 2 + q) * 512;       // wave-uniform LDS base (shorts)
            gld16(A0 + (size_t)(rowBase + r) * lda + k0 + ko, &As[lb]);
            gld16(B0 + (size_t)(colBase + r) * ldb + k0 + ko, &Bs[lb]);
            if (SPLIT) {
                gld16(A1 + (size_t)(rowBase + r) * lda + k0 + ko, &As2[lb]);
                gld16(B1 + (size_t)(colBase + r) * ldb + k0 + ko, &Bs2[lb]);
            }
        }
        __syncthreads();

        bfrag af[4], bf_[4];
        const int aoff = quad * 8;
        #pragma unroll
        for (int i = 0; i < 4; ++i) {
            af[i]  = *(const bfrag*)&As[(wy * 64 + i * 16 + lcol) * 32 + aoff];
            bf_[i] = *(const bfrag*)&Bs[(wx * 64 + i * 16 + lcol) * 32 + aoff];
        }
        #pragma unroll
        for (int i = 0; i < 4; ++i)
            #pragma unroll
            for (int j = 0; j < 4; ++j)
                acc[i][j] = __builtin_amdgcn_mfma_f32_16x16x32_bf16(af[i], bf_[j], acc[i][j], 0, 0, 0);

        if (SPLIT) {
            bfrag al[4], bl[4];
            #pragma unroll
            for (int i = 0; i < 4; ++i) {
                al[i] = *(const bfrag*)&As2[(wy * 64 + i * 16 + lcol) * 32 + aoff];
                bl[i] = *(const bfrag*)&Bs2[(wx * 64 + i * 16 + lcol) * 32 + aoff];
            }
            #pragma unroll
            for (int i = 0; i < 4; ++i)
                #pragma unroll
                for (int j = 0; j < 4; ++j) {
                    acc[i][j] = __builtin_amdgcn_mfma_f32_16x16x32_bf16(af[i], bl[j], acc[i][j], 0, 0, 0);
                    acc[i][j] = __builtin_amdgcn_mfma_f32_16x16x32_bf16(al[i], bf_[j], acc[i][j], 0, 0, 0);
                }
        }
    }

    // C/D layout: col = lane&15, row = quad*4 + reg   [verified m89/m91]
    const int crow0 = rowBase + wy * 64 + quad * 4;
    const int ccol0 = colBase + wx * 64 + lcol;

    if (EPI == 0) {            // scores: S = acc * mask, fp32
        float* C = (float*)Cout + (size_t)b * sC;
        const float* Mk = aux + (size_t)b * sAux;
        #pragma unroll
        for (int i = 0; i < 4; ++i)
            #pragma unroll
            for (int j = 0; j < 4; ++j)
                #pragma unroll
                for (int r = 0; r < 4; ++r) {
                    const int row = crow0 + i * 16 + r;
                    const int col = ccol0 + j * 16;
                    C[(size_t)row * ldc + col] =
                        acc[i][j][r] * Mk[(size_t)row * ldaux + col];
                }
    } else if (EPI == 1) {     // v^T: bf16, vT[b][c][m] = acc + bias[c]
        short* C = (short*)Cout;
        #pragma unroll
        for (int j = 0; j < 4; ++j) {
            const int col = ccol0 + j * 16;          // c index
            const float bi = aux[col];
            #pragma unroll
            for (int i = 0; i < 4; ++i) {
                const int rowb = crow0 + i * 16;     // flattened b*M + m
                const int bb = rowb >> 11, ml = rowb & 2047;
                s4v st;
                #pragma unroll
                for (int r = 0; r < 4; ++r) st[r] = (short)f2bf(acc[i][j][r] + bi);
                *(s4v*)(C + (size_t)bb * ((size_t)Cc * Mm) + (size_t)col * Mm + ml) = st;
            }
        }
    } else if (EPI == 2) {     // gate: g = dec*(1+tanh(acc)), bf16
        short* C = (short*)Cout + (size_t)b * sC;
        const float* Dg = aux + (size_t)b * sAux;
        #pragma unroll
        for (int i = 0; i < 4; ++i)
            #pragma unroll
            for (int j = 0; j < 4; ++j)
                #pragma unroll
                for (int r = 0; r < 4; ++r) {
                    const int row = crow0 + i * 16 + r;
                    const int col = ccol0 + j * 16;
                    const float a = acc[i][j][r];
                    const float t = 1.f - 2.f / (__expf(2.f * a) + 1.f);
                    const float g = Dg[(size_t)row * ldaux + col] * (1.f + t);
                    C[(size_t)row * ldc + col] = (short)f2bf(g);
                }
    } else if (EPI == 3) {     // relu(acc+bias), bf16
        short* C = (short*)Cout;
        #pragma unroll
        for (int i = 0; i < 4; ++i)
            #pragma unroll
            for (int j = 0; j < 4; ++j) {
                const int col = ccol0 + j * 16;
                const float bi = aux[col];
                #pragma unroll
                for (int r = 0; r < 4; ++r) {
                    const int row = crow0 + i * 16 + r;
                    C[(size_t)row * ldc + col] = (short)f2bf(fmaxf(acc[i][j][r] + bi, 0.f));
                }
            }
    } else {                   // EPI 4: acc+bias, fp32 out
        float* C = (float*)Cout;
        #pragma unroll
        for (int i = 0; i < 4; ++i)
            #pragma unroll
            for (int j = 0; j < 4; ++j) {
                const int col = ccol0 + j * 16;
                const float bi = aux[col];
                #pragma unroll
                for (int r = 0; r < 4; ++r) {
                    const int row = crow0 + i * 16 + r;
                    C[(size_t)row * ldc + col] = acc[i][j][r] + bi;
                }
            }
    }
}

// ---------------------------------------------------------------------------
// Masked softmax over fp32 S row; writes P as bf16 IN PLACE (first 4KB of the
// row's 8KB slot). All reads complete before the first barrier -> safe.
// ---------------------------------------------------------------------------
__global__ __launch_bounds__(256) void softmax_kernel(float* __restrict__ S)
{
    float* p = S + (size_t)blockIdx.x * Mm;
    const int tid = threadIdx.x;
    const int wv = tid >> 6, ln = tid & 63;

    float4 a = *(const float4*)(p + tid * 4);
    float4 c = *(const float4*)(p + 1024 + tid * 4);

    float mx = fmaxf(fmaxf(fmaxf(a.x, a.y), fmaxf(a.z, a.w)),
                     fmaxf(fmaxf(c.x, c.y), fmaxf(c.z, c.w)));
    #pragma unroll
    for (int off = 32; off >= 1; off >>= 1)
        mx = fmaxf(mx, __shfl_xor(mx, off, 64));

    __shared__ float sm[4], ss[4];
    if (ln == 0) sm[wv] = mx;
    __syncthreads();
    mx = fmaxf(fmaxf(sm[0], sm[1]), fmaxf(sm[2], sm[3]));

    float e[8];
    e[0] = __expf(a.x - mx); e[1] = __expf(a.y - mx);
    e[2] = __expf(a.z - mx); e[3] = __expf(a.w - mx);
    e[4] = __expf(c.x - mx); e[5] = __expf(c.y - mx);
    e[6] = __expf(c.z - mx); e[7] = __expf(c.w - mx);
    float s = e[0]+e[1]+e[2]+e[3]+e[4]+e[5]+e[6]+e[7];
    #pragma unroll
    for (int off = 32; off >= 1; off >>= 1)
        s += __shfl_xor(s, off, 64);
    if (ln == 0) ss[wv] = s;
    __syncthreads();
    s = ss[0] + ss[1] + ss[2] + ss[3];

    const float inv = 1.0f / s;
    s4v o1, o2;
    o1[0] = (a.x == 0.f) ? 0 : (short)f2bf(e[0] * inv);
    o1[1] = (a.y == 0.f) ? 0 : (short)f2bf(e[1] * inv);
    o1[2] = (a.z == 0.f) ? 0 : (short)f2bf(e[2] * inv);
    o1[3] = (a.w == 0.f) ? 0 : (short)f2bf(e[3] * inv);
    o2[0] = (c.x == 0.f) ? 0 : (short)f2bf(e[4] * inv);
    o2[1] = (c.y == 0.f) ? 0 : (short)f2bf(e[5] * inv);
    o2[2] = (c.z == 0.f) ? 0 : (short)f2bf(e[6] * inv);
    o2[3] = (c.w == 0.f) ? 0 : (short)f2bf(e[7] * inv);
    short* P = (short*)p;
    *(s4v*)(P + tid * 4) = o1;
    *(s4v*)(P + 1024 + tid * 4) = o2;
}

// fp32 -> bf16 hi/lo split, vectorized x4. grid*256*4 == element count.
__global__ __launch_bounds__(256) void sconv(const float* __restrict__ x,
                                             short* __restrict__ hi,
                                             short* __restrict__ lo)
{
    const size_t i = (size_t)blockIdx.x * 256 + threadIdx.x;
    f4 v = ((const f4*)x)[i];
    s4v h, l;
    #pragma unroll
    for (int k = 0; k < 4; ++k) {
        unsigned short hb = f2bf(v[k]);
        h[k] = (short)hb;
        l[k] = (short)f2bf(v[k] - bf2f(hb));
    }
    ((s4v*)hi)[i] = h;
    ((s4v*)lo)[i] = l;
}

// W [512,512] fp32 -> Wt [512,512] bf16 transposed (Wt[n][k] = W[k][n]).
__global__ __launch_bounds__(256) void wconv(const float* s0, const float* s1, const float* s2,
                                             short* d0, short* d1, short* d2)
{
    const float* Sm = blockIdx.z == 0 ? s0 : blockIdx.z == 1 ? s1 : s2;
    short* D = blockIdx.z == 0 ? d0 : blockIdx.z == 1 ? d1 : d2;
    __shared__ float t[32][33];
    const int x = threadIdx.x & 31, y = threadIdx.x >> 5;
    const int gx = blockIdx.x * 32, gy = blockIdx.y * 32;
    #pragma unroll
    for (int yy = y; yy < 32; yy += 8)
        t[yy][x] = Sm[(size_t)(gy + yy) * 512 + gx + x];
    __syncthreads();
    #pragma unroll
    for (int yy = y; yy < 32; yy += 8)
        D[(size_t)(gx + yy) * 512 + gy + x] = (short)f2bf(t[x][yy]);
}

// ---------------------------------------------------------------------------
// ws budget: exactly 160 MiB (the R1-proven size). d_out doubles as scratch.
//   ws [0,128MiB)  : S fp32 (rows 8KB). P bf16 in-place (lower 4KB halves).
//                    g bf16 -> upper 4KB halves (PV). h bf16 -> lower halves
//                    (fc1, after P dead). No cross-row reads of upper halves.
//   ws [128,144MiB): dec_hi; after score: Wvt/W1t/W2t (1.5 MiB, wconv runs
//                    post-score).
//   ws [144,160MiB): dec_lo; after score: vT (16 MiB).
//   d_out [0,16MiB): enc_hi; [16,32MiB): enc_lo; both dead before fc2 writes.
// ---------------------------------------------------------------------------
extern "C" void kernel_launch(void* const* d_in, const int* in_sizes, int n_in,
                              void* d_out, int out_size, void* d_ws, size_t ws_size,
                              hipStream_t stream)
{
    const float* dec   = (const float*)d_in[0];
    const float* enc   = (const float*)d_in[1];
    const float* trans = (const float*)d_in[2];
    const float* Wv = (const float*)d_in[3];
    const float* bv = (const float*)d_in[4];
    const float* W1 = (const float*)d_in[5];
    const float* b1 = (const float*)d_in[6];
    const float* W2 = (const float*)d_in[7];
    const float* b2 = (const float*)d_in[8];

    char* ws = (char*)d_ws;
    float* S      = (float*)ws;                     // 128 MiB
    short* P      = (short*)ws;                     // row stride 4096 shorts
    short* g      = P + 2048;                       // upper halves, ld 4096
    short* h      = P;                              // lower halves, ld 4096
    short* dec_hi = (short*)(ws + 134217728);       // [128,144) MiB
    short* dec_lo = (short*)(ws + 150994944);       // [144,160) MiB
    short* Wvt    = dec_hi;                         // post-score aliases
    short* W1t    = dec_hi + 262144;
    short* W2t    = dec_hi + 524288;
    short* vT     = dec_lo;
    short* enc_hi = (short*)d_out;                  // d_out as scratch
    short* enc_lo = enc_hi + 8388608;

    sconv<<<dim3(8192), 256, 0, stream>>>(dec, dec_hi, dec_lo);
    sconv<<<dim3(8192), 256, 0, stream>>>(enc, enc_hi, enc_lo);

    // S = (dec @ enc^T) * mask   (bf16x3 split, fp32 out)
    gemm_mfma<0, true><<<dim3(16, 16, 8), 256, 0, stream>>>(
        dec_hi, dec_lo, (long)Nn * Cc, 512,
        enc_hi, enc_lo, (long)Mm * Cc, 512,
        trans, (long)Nn * Mm, 2048, S, (long)Nn * Mm, 2048, 512);

    // masked softmax, P bf16 in place (row stride 4096 shorts)
    softmax_kernel<<<dim3(Bb * Nn), 256, 0, stream>>>(S);

    // weights bf16-transposed into dec_hi region (dead after score)
    wconv<<<dim3(16, 16, 3), 256, 0, stream>>>(Wv, W1, W2, Wvt, W1t, W2t);

    // v^T = (enc @ Wv + bv)^T  [B][C][M] bf16, into dec_lo region
    gemm_mfma<1, false><<<dim3(4, 128, 1), 256, 0, stream>>>(
        enc_hi, nullptr, 0, 512, Wvt, nullptr, 0, 512, bv, 0, 0, vT, 0, 0, 512);

    // g = dec * (1 + tanh(P @ v))   bf16 -> upper halves of S rows
    gemm_mfma<2, false><<<dim3(4, 16, 8), 256, 0, stream>>>(
        P, nullptr, (long)Nn * 4096, 4096,
        vT, nullptr, (long)Cc * Mm, 2048,
        dec, (long)Nn * Cc, 512, g, (long)Nn * 4096, 4096, 2048);

    // h = relu(g @ W1 + b1)   bf16 -> lower halves (P dead)
    gemm_mfma<3, false><<<dim3(4, 128, 1), 256, 0, stream>>>(
        g, nullptr, 0, 4096, W1t, nullptr, 0, 512, b1, 0, 0, h, 0, 4096, 512);

    // out = h @ W2 + b2   fp32 (overwrites enc_hi/lo scratch)
    gemm_mfma<4, false><<<dim3(4, 128, 1), 256, 0, stream>>>(
        h, nullptr, 0, 4096, W2t, nullptr, 0, 512, b2, 0, 0, d_out, 0, 512, 512);
}

// Round 4
// 614.445 us; speedup vs baseline: 2.3394x; 1.0452x over previous
//
#include <hip/hip_runtime.h>
#include <math.h>

#define Bb 8
#define Nn 2048
#define Mm 2048
#define Cc 512

typedef __attribute__((ext_vector_type(8))) short bfrag;   // 8 bf16 = 4 VGPRs
typedef __attribute__((ext_vector_type(4))) float f4;      // MFMA acc
typedef __attribute__((ext_vector_type(4))) short s4v;

__device__ __forceinline__ unsigned short f2bf(float f) {
    unsigned u = __float_as_uint(f);
    u += 0x7fff + ((u >> 16) & 1);          // RNE
    return (unsigned short)(u >> 16);
}
__device__ __forceinline__ float bf2f(unsigned short s) {
    return __uint_as_float(((unsigned)s) << 16);
}

__device__ __forceinline__ void gld16(const void* g, void* l) {
    __builtin_amdgcn_global_load_lds(
        (const __attribute__((address_space(1))) void*)g,
        (__attribute__((address_space(3))) void*)l, 16, 0, 0);
}

// ---------------------------------------------------------------------------
// MFMA GEMM, 128xBN tile, BK=32, 256 threads.
//   BN=128: 4 waves in 2x2, each 64x64 (acc 4x4)  — identical to R3.
//   BN=64 : 4 waves stacked on rows, each 32x64 (acc 2x4) — doubles grid for
//           occupancy on the small GEMMs (2 -> 4 blocks/CU).
// A [rows,K] bf16 row-major (lda elems, k contiguous).
// Bt [cols,K] bf16 row-major (ldb elems, k contiguous)  == B pre-transposed.
// SPLIT (BN=128 only): acc = ah*bh + ah*bl + al*bh  (fp32-like scores).
// EPI: 0=score (*mask, fp32 out)  1=vT (bias, bf16 transposed out)
//      2=gate (dec*(1+tanh), bf16 out)  3=relu+bias bf16  4=bias fp32 out
// ---------------------------------------------------------------------------
template<int EPI, bool SPLIT, int BN>
__global__ __launch_bounds__(256) void gemm_mfma(
    const short* __restrict__ Ah, const short* __restrict__ Al, long sA, int lda,
    const short* __restrict__ Bh, const short* __restrict__ Bl, long sB, int ldb,
    const float* __restrict__ aux, long sAux, int ldaux,
    void* __restrict__ Cout, long sC, int ldc, int K)
{
    constexpr int NI = (BN == 128) ? 4 : 2;      // row frags per wave
    constexpr int NQ = (512 + BN * 4) / 256;     // staging chunks / 256

    __shared__ short As[128 * 32];
    __shared__ short Bs[BN * 32];
    __shared__ short As2[SPLIT ? 128 * 32 : 2];
    __shared__ short Bs2[SPLIT ? BN * 32 : 2];

    const int b = blockIdx.z;
    const short* A0 = Ah + (size_t)b * sA;
    const short* B0 = Bh + (size_t)b * sB;
    const short* A1 = SPLIT ? (Al + (size_t)b * sA) : (const short*)nullptr;
    const short* B1 = SPLIT ? (Bl + (size_t)b * sB) : (const short*)nullptr;

    const int tid  = threadIdx.x;
    const int wv   = tid >> 6;
    const int ln   = tid & 63;
    const int wx   = (BN == 128) ? (wv & 1) : 0;
    const int wy   = (BN == 128) ? (wv >> 1) : wv;
    const int lcol = ln & 15, quad = ln >> 4;
    const int row0w = wy * (NI * 16);
    const int col0w = wx * 64;

    const int rowBase = blockIdx.y * 128;
    const int colBase = blockIdx.x * BN;

    f4 acc[NI][4];
    const f4 z4 = {0.f, 0.f, 0.f, 0.f};
    #pragma unroll
    for (int i = 0; i < NI; ++i)
        #pragma unroll
        for (int j = 0; j < 4; ++j) acc[i][j] = z4;

    for (int k0 = 0; k0 < K; k0 += 32) {
        __syncthreads();
        #pragma unroll
        for (int q = 0; q < NQ; ++q) {
            const int c0 = q * 256 + wv * 64;    // wave-uniform chunk base
            const int c  = c0 + ln;
            if (c0 < 512) {                      // A-side (uniform branch)
                const int r  = c >> 2;
                const int ko = (c & 3) * 8;
                gld16(A0 + (size_t)(rowBase + r) * lda + k0 + ko, &As[c0 * 8]);
                if (SPLIT)
                    gld16(A1 + (size_t)(rowBase + r) * lda + k0 + ko, &As2[c0 * 8]);
            } else {                             // B-side
                const int cb = c - 512;
                const int r  = cb >> 2;
                const int ko = (cb & 3) * 8;
                gld16(B0 + (size_t)(colBase + r) * ldb + k0 + ko, &Bs[(c0 - 512) * 8]);
                if (SPLIT)
                    gld16(B1 + (size_t)(colBase + r) * ldb + k0 + ko, &Bs2[(c0 - 512) * 8]);
            }
        }
        __syncthreads();

        bfrag af[NI], bf_[4];
        const int aoff = quad * 8;
        #pragma unroll
        for (int i = 0; i < NI; ++i)
            af[i]  = *(const bfrag*)&As[(row0w + i * 16 + lcol) * 32 + aoff];
        #pragma unroll
        for (int j = 0; j < 4; ++j)
            bf_[j] = *(const bfrag*)&Bs[(col0w + j * 16 + lcol) * 32 + aoff];
        #pragma unroll
        for (int i = 0; i < NI; ++i)
            #pragma unroll
            for (int j = 0; j < 4; ++j)
                acc[i][j] = __builtin_amdgcn_mfma_f32_16x16x32_bf16(af[i], bf_[j], acc[i][j], 0, 0, 0);

        if (SPLIT) {
            bfrag al[NI], bl[4];
            #pragma unroll
            for (int i = 0; i < NI; ++i)
                al[i] = *(const bfrag*)&As2[(row0w + i * 16 + lcol) * 32 + aoff];
            #pragma unroll
            for (int j = 0; j < 4; ++j)
                bl[j] = *(const bfrag*)&Bs2[(col0w + j * 16 + lcol) * 32 + aoff];
            #pragma unroll
            for (int i = 0; i < NI; ++i)
                #pragma unroll
                for (int j = 0; j < 4; ++j) {
                    acc[i][j] = __builtin_amdgcn_mfma_f32_16x16x32_bf16(af[i], bl[j], acc[i][j], 0, 0, 0);
                    acc[i][j] = __builtin_amdgcn_mfma_f32_16x16x32_bf16(al[i], bf_[j], acc[i][j], 0, 0, 0);
                }
        }
    }

    // C/D layout: col = lane&15, row = quad*4 + reg   [verified m89/m91]
    const int crow0 = rowBase + row0w + quad * 4;
    const int ccol0 = colBase + col0w + lcol;

    if (EPI == 0) {            // scores: S = acc * mask, fp32
        float* C = (float*)Cout + (size_t)b * sC;
        const float* Mk = aux + (size_t)b * sAux;
        #pragma unroll
        for (int i = 0; i < NI; ++i)
            #pragma unroll
            for (int j = 0; j < 4; ++j)
                #pragma unroll
                for (int r = 0; r < 4; ++r) {
                    const int row = crow0 + i * 16 + r;
                    const int col = ccol0 + j * 16;
                    C[(size_t)row * ldc + col] =
                        acc[i][j][r] * Mk[(size_t)row * ldaux + col];
                }
    } else if (EPI == 1) {     // v^T: bf16, vT[b][c][m] = acc + bias[c]
        short* C = (short*)Cout;
        #pragma unroll
        for (int j = 0; j < 4; ++j) {
            const int col = ccol0 + j * 16;          // c index
            const float bi = aux[col];
            #pragma unroll
            for (int i = 0; i < NI; ++i) {
                const int rowb = crow0 + i * 16;     // flattened b*M + m
                const int bb = rowb >> 11, ml = rowb & 2047;
                s4v st;
                #pragma unroll
                for (int r = 0; r < 4; ++r) st[r] = (short)f2bf(acc[i][j][r] + bi);
                *(s4v*)(C + (size_t)bb * ((size_t)Cc * Mm) + (size_t)col * Mm + ml) = st;
            }
        }
    } else if (EPI == 2) {     // gate: g = dec*(1+tanh(acc)), bf16
        short* C = (short*)Cout + (size_t)b * sC;
        const float* Dg = aux + (size_t)b * sAux;
        #pragma unroll
        for (int i = 0; i < NI; ++i)
            #pragma unroll
            for (int j = 0; j < 4; ++j)
                #pragma unroll
                for (int r = 0; r < 4; ++r) {
                    const int row = crow0 + i * 16 + r;
                    const int col = ccol0 + j * 16;
                    const float a = acc[i][j][r];
                    const float t = 1.f - 2.f / (__expf(2.f * a) + 1.f);
                    const float g = Dg[(size_t)row * ldaux + col] * (1.f + t);
                    C[(size_t)row * ldc + col] = (short)f2bf(g);
                }
    } else if (EPI == 3) {     // relu(acc+bias), bf16
        short* C = (short*)Cout;
        #pragma unroll
        for (int i = 0; i < NI; ++i)
            #pragma unroll
            for (int j = 0; j < 4; ++j) {
                const int col = ccol0 + j * 16;
                const float bi = aux[col];
                #pragma unroll
                for (int r = 0; r < 4; ++r) {
                    const int row = crow0 + i * 16 + r;
                    C[(size_t)row * ldc + col] = (short)f2bf(fmaxf(acc[i][j][r] + bi, 0.f));
                }
            }
    } else {                   // EPI 4: acc+bias, fp32 out
        float* C = (float*)Cout;
        #pragma unroll
        for (int i = 0; i < NI; ++i)
            #pragma unroll
            for (int j = 0; j < 4; ++j) {
                const int col = ccol0 + j * 16;
                const float bi = aux[col];
                #pragma unroll
                for (int r = 0; r < 4; ++r) {
                    const int row = crow0 + i * 16 + r;
                    C[(size_t)row * ldc + col] = acc[i][j][r] + bi;
                }
            }
    }
}

// ---------------------------------------------------------------------------
// Masked softmax over fp32 S row; writes P as bf16 IN PLACE (lower 4KB of the
// row's 8KB slot). All reads complete before the stores -> safe.
// ---------------------------------------------------------------------------
__global__ __launch_bounds__(256) void softmax_kernel(float* __restrict__ S)
{
    float* p = S + (size_t)blockIdx.x * Mm;
    const int tid = threadIdx.x;
    const int wv = tid >> 6, ln = tid & 63;

    float4 a = *(const float4*)(p + tid * 4);
    float4 c = *(const float4*)(p + 1024 + tid * 4);

    float mx = fmaxf(fmaxf(fmaxf(a.x, a.y), fmaxf(a.z, a.w)),
                     fmaxf(fmaxf(c.x, c.y), fmaxf(c.z, c.w)));
    #pragma unroll
    for (int off = 32; off >= 1; off >>= 1)
        mx = fmaxf(mx, __shfl_xor(mx, off, 64));

    __shared__ float sm[4], ss[4];
    if (ln == 0) sm[wv] = mx;
    __syncthreads();
    mx = fmaxf(fmaxf(sm[0], sm[1]), fmaxf(sm[2], sm[3]));

    float e[8];
    e[0] = __expf(a.x - mx); e[1] = __expf(a.y - mx);
    e[2] = __expf(a.z - mx); e[3] = __expf(a.w - mx);
    e[4] = __expf(c.x - mx); e[5] = __expf(c.y - mx);
    e[6] = __expf(c.z - mx); e[7] = __expf(c.w - mx);
    float s = e[0]+e[1]+e[2]+e[3]+e[4]+e[5]+e[6]+e[7];
    #pragma unroll
    for (int off = 32; off >= 1; off >>= 1)
        s += __shfl_xor(s, off, 64);
    if (ln == 0) ss[wv] = s;
    __syncthreads();
    s = ss[0] + ss[1] + ss[2] + ss[3];

    const float inv = 1.0f / s;
    s4v o1, o2;
    o1[0] = (a.x == 0.f) ? 0 : (short)f2bf(e[0] * inv);
    o1[1] = (a.y == 0.f) ? 0 : (short)f2bf(e[1] * inv);
    o1[2] = (a.z == 0.f) ? 0 : (short)f2bf(e[2] * inv);
    o1[3] = (a.w == 0.f) ? 0 : (short)f2bf(e[3] * inv);
    o2[0] = (c.x == 0.f) ? 0 : (short)f2bf(e[4] * inv);
    o2[1] = (c.y == 0.f) ? 0 : (short)f2bf(e[5] * inv);
    o2[2] = (c.z == 0.f) ? 0 : (short)f2bf(e[6] * inv);
    o2[3] = (c.w == 0.f) ? 0 : (short)f2bf(e[7] * inv);
    short* P = (short*)p;
    *(s4v*)(P + tid * 4) = o1;
    *(s4v*)(P + 1024 + tid * 4) = o2;
}

// fp32 -> bf16 hi/lo split, vectorized x4. grid*256*4 == element count.
__global__ __launch_bounds__(256) void sconv(const float* __restrict__ x,
                                             short* __restrict__ hi,
                                             short* __restrict__ lo)
{
    const size_t i = (size_t)blockIdx.x * 256 + threadIdx.x;
    f4 v = ((const f4*)x)[i];
    s4v h, l;
    #pragma unroll
    for (int k = 0; k < 4; ++k) {
        unsigned short hb = f2bf(v[k]);
        h[k] = (short)hb;
        l[k] = (short)f2bf(v[k] - bf2f(hb));
    }
    ((s4v*)hi)[i] = h;
    ((s4v*)lo)[i] = l;
}

// W [512,512] fp32 -> Wt [512,512] bf16 transposed (Wt[n][k] = W[k][n]).
__global__ __launch_bounds__(256) void wconv(const float* s0, const float* s1, const float* s2,
                                             short* d0, short* d1, short* d2)
{
    const float* Sm = blockIdx.z == 0 ? s0 : blockIdx.z == 1 ? s1 : s2;
    short* D = blockIdx.z == 0 ? d0 : blockIdx.z == 1 ? d1 : d2;
    __shared__ float t[32][33];
    const int x = threadIdx.x & 31, y = threadIdx.x >> 5;
    const int gx = blockIdx.x * 32, gy = blockIdx.y * 32;
    #pragma unroll
    for (int yy = y; yy < 32; yy += 8)
        t[yy][x] = Sm[(size_t)(gy + yy) * 512 + gx + x];
    __syncthreads();
    #pragma unroll
    for (int yy = y; yy < 32; yy += 8)
        D[(size_t)(gx + yy) * 512 + gy + x] = (short)f2bf(t[x][yy]);
}

// ---------------------------------------------------------------------------
// ws budget: exactly 160 MiB (the R1-proven size). d_out doubles as scratch.
//   ws [0,128MiB)  : S fp32 (rows 8KB). P bf16 in-place (lower 4KB halves).
//                    g bf16 -> upper 4KB halves (PV). h bf16 -> lower halves
//                    (fc1, after P dead). No cross-row reads of upper halves.
//   ws [128,144MiB): dec_hi; after score: Wvt/W1t/W2t (wconv runs post-score).
//   ws [144,160MiB): dec_lo; after score: vT (16 MiB).
//   d_out [0,16MiB): enc_hi; [16,32MiB): enc_lo; both dead before fc2 writes.
// ---------------------------------------------------------------------------
extern "C" void kernel_launch(void* const* d_in, const int* in_sizes, int n_in,
                              void* d_out, int out_size, void* d_ws, size_t ws_size,
                              hipStream_t stream)
{
    const float* dec   = (const float*)d_in[0];
    const float* enc   = (const float*)d_in[1];
    const float* trans = (const float*)d_in[2];
    const float* Wv = (const float*)d_in[3];
    const float* bv = (const float*)d_in[4];
    const float* W1 = (const float*)d_in[5];
    const float* b1 = (const float*)d_in[6];
    const float* W2 = (const float*)d_in[7];
    const float* b2 = (const float*)d_in[8];

    char* ws = (char*)d_ws;
    float* S      = (float*)ws;                     // 128 MiB
    short* P      = (short*)ws;                     // row stride 4096 shorts
    short* g      = P + 2048;                       // upper halves, ld 4096
    short* h      = P;                              // lower halves, ld 4096
    short* dec_hi = (short*)(ws + 134217728);       // [128,144) MiB
    short* dec_lo = (short*)(ws + 150994944);       // [144,160) MiB
    short* Wvt    = dec_hi;                         // post-score aliases
    short* W1t    = dec_hi + 262144;
    short* W2t    = dec_hi + 524288;
    short* vT     = dec_lo;
    short* enc_hi = (short*)d_out;                  // d_out as scratch
    short* enc_lo = enc_hi + 8388608;

    sconv<<<dim3(8192), 256, 0, stream>>>(dec, dec_hi, dec_lo);
    sconv<<<dim3(8192), 256, 0, stream>>>(enc, enc_hi, enc_lo);

    // S = (dec @ enc^T) * mask   (bf16x3 split, fp32 out)  BN=128 path
    gemm_mfma<0, true, 128><<<dim3(16, 16, 8), 256, 0, stream>>>(
        dec_hi, dec_lo, (long)Nn * Cc, 512,
        enc_hi, enc_lo, (long)Mm * Cc, 512,
        trans, (long)Nn * Mm, 2048, S, (long)Nn * Mm, 2048, 512);

    // masked softmax, P bf16 in place (row stride 4096 shorts)
    softmax_kernel<<<dim3(Bb * Nn), 256, 0, stream>>>(S);

    // weights bf16-transposed into dec_hi region (dead after score)
    wconv<<<dim3(16, 16, 3), 256, 0, stream>>>(Wv, W1, W2, Wvt, W1t, W2t);

    // v^T = (enc @ Wv + bv)^T  [B][C][M] bf16, into dec_lo region
    gemm_mfma<1, false, 64><<<dim3(8, 128, 1), 256, 0, stream>>>(
        enc_hi, nullptr, 0, 512, Wvt, nullptr, 0, 512, bv, 0, 0, vT, 0, 0, 512);

    // g = dec * (1 + tanh(P @ v))   bf16 -> upper halves of S rows
    gemm_mfma<2, false, 64><<<dim3(8, 16, 8), 256, 0, stream>>>(
        P, nullptr, (long)Nn * 4096, 4096,
        vT, nullptr, (long)Cc * Mm, 2048,
        dec, (long)Nn * Cc, 512, g, (long)Nn * 4096, 4096, 2048);

    // h = relu(g @ W1 + b1)   bf16 -> lower halves (P dead)
    gemm_mfma<3, false, 64><<<dim3(8, 128, 1), 256, 0, stream>>>(
        g, nullptr, 0, 4096, W1t, nullptr, 0, 512, b1, 0, 0, h, 0, 4096, 512);

    // out = h @ W2 + b2   fp32 (overwrites enc_hi/lo scratch)
    gemm_mfma<4, false, 64><<<dim3(8, 128, 1), 256, 0, stream>>>(
        h, nullptr, 0, 4096, W2t, nullptr, 0, 512, b2, 0, 0, d_out, 0, 512, 512);
}

// Round 5
// 556.618 us; speedup vs baseline: 2.5824x; 1.1039x over previous
//
#include <hip/hip_runtime.h>
#include <math.h>

#define Bb 8
#define Nn 2048
#define Mm 2048
#define Cc 512

typedef __attribute__((ext_vector_type(8))) _Float16 hfrag;  // 8 f16 = 4 VGPRs
typedef __attribute__((ext_vector_type(4))) float f4;        // MFMA acc
typedef __attribute__((ext_vector_type(4))) _Float16 h4;

__device__ __forceinline__ void gld16(const void* g, void* l) {
    __builtin_amdgcn_global_load_lds(
        (const __attribute__((address_space(1))) void*)g,
        (__attribute__((address_space(3))) void*)l, 16, 0, 0);
}

// ---------------------------------------------------------------------------
// MFMA GEMM (fp16 in, fp32 acc), 128xBN tile, BK=32, 256 threads.
//   BN=128: 4 waves 2x2, each 64x64 (acc 4x4)  — m97 structure.
//   BN=64 : 4 waves row-stacked, each 32x64 (acc 2x4) — 2x grid for small GEMMs.
// A [rows,K] f16 row-major (lda elems, k contiguous).
// Bt [cols,K] f16 row-major (ldb elems)  == B pre-transposed.
// EPI: 0=score (*mask, fp32 out)  1=vT (bias, f16 transposed out)
//      2=gate (dec*(1+tanh), f16 out)  3=relu+bias f16  4=bias fp32 out
// ---------------------------------------------------------------------------
template<int EPI, int BN>
__global__ __launch_bounds__(256) void gemm_mfma(
    const _Float16* __restrict__ Ah, long sA, int lda,
    const _Float16* __restrict__ Bh, long sB, int ldb,
    const float* __restrict__ aux, long sAux, int ldaux,
    void* __restrict__ Cout, long sC, int ldc, int K)
{
    constexpr int NI = (BN == 128) ? 4 : 2;      // row frags per wave
    constexpr int NQ = (512 + BN * 4) / 256;     // 16B staging chunks / 256

    __shared__ _Float16 As[128 * 32];
    __shared__ _Float16 Bs[BN * 32];

    const int b = blockIdx.z;
    const _Float16* A0 = Ah + (size_t)b * sA;
    const _Float16* B0 = Bh + (size_t)b * sB;

    const int tid  = threadIdx.x;
    const int wv   = tid >> 6;
    const int ln   = tid & 63;
    const int wx   = (BN == 128) ? (wv & 1) : 0;
    const int wy   = (BN == 128) ? (wv >> 1) : wv;
    const int lcol = ln & 15, quad = ln >> 4;
    const int row0w = wy * (NI * 16);
    const int col0w = wx * 64;

    const int rowBase = blockIdx.y * 128;
    const int colBase = blockIdx.x * BN;

    f4 acc[NI][4];
    const f4 z4 = {0.f, 0.f, 0.f, 0.f};
    #pragma unroll
    for (int i = 0; i < NI; ++i)
        #pragma unroll
        for (int j = 0; j < 4; ++j) acc[i][j] = z4;

    for (int k0 = 0; k0 < K; k0 += 32) {
        __syncthreads();
        #pragma unroll
        for (int q = 0; q < NQ; ++q) {
            const int c0 = q * 256 + wv * 64;    // wave-uniform chunk base
            const int c  = c0 + ln;
            if (c0 < 512) {                      // A-side (uniform branch)
                const int r  = c >> 2;
                const int ko = (c & 3) * 8;
                gld16(A0 + (size_t)(rowBase + r) * lda + k0 + ko, &As[c0 * 8]);
            } else {                             // B-side
                const int cb = c - 512;
                const int r  = cb >> 2;
                const int ko = (cb & 3) * 8;
                gld16(B0 + (size_t)(colBase + r) * ldb + k0 + ko, &Bs[(c0 - 512) * 8]);
            }
        }
        __syncthreads();

        hfrag af[NI], bf_[4];
        const int aoff = quad * 8;
        #pragma unroll
        for (int i = 0; i < NI; ++i)
            af[i]  = *(const hfrag*)&As[(row0w + i * 16 + lcol) * 32 + aoff];
        #pragma unroll
        for (int j = 0; j < 4; ++j)
            bf_[j] = *(const hfrag*)&Bs[(col0w + j * 16 + lcol) * 32 + aoff];
        #pragma unroll
        for (int i = 0; i < NI; ++i)
            #pragma unroll
            for (int j = 0; j < 4; ++j)
                acc[i][j] = __builtin_amdgcn_mfma_f32_16x16x32_f16(af[i], bf_[j], acc[i][j], 0, 0, 0);
    }

    // C/D layout: col = lane&15, row = quad*4 + reg   [verified m89/m91]
    const int crow0 = rowBase + row0w + quad * 4;
    const int ccol0 = colBase + col0w + lcol;

    if (EPI == 0) {            // scores: S = acc * mask, fp32
        float* C = (float*)Cout + (size_t)b * sC;
        const float* Mk = aux + (size_t)b * sAux;
        #pragma unroll
        for (int i = 0; i < NI; ++i)
            #pragma unroll
            for (int j = 0; j < 4; ++j)
                #pragma unroll
                for (int r = 0; r < 4; ++r) {
                    const int row = crow0 + i * 16 + r;
                    const int col = ccol0 + j * 16;
                    C[(size_t)row * ldc + col] =
                        acc[i][j][r] * Mk[(size_t)row * ldaux + col];
                }
    } else if (EPI == 1) {     // v^T: f16, vT[b][c][m] = acc + bias[c]
        _Float16* C = (_Float16*)Cout;
        #pragma unroll
        for (int j = 0; j < 4; ++j) {
            const int col = ccol0 + j * 16;          // c index
            const float bi = aux[col];
            #pragma unroll
            for (int i = 0; i < NI; ++i) {
                const int rowb = crow0 + i * 16;     // flattened b*M + m
                const int bb = rowb >> 11, ml = rowb & 2047;
                h4 st;
                #pragma unroll
                for (int r = 0; r < 4; ++r) st[r] = (_Float16)(acc[i][j][r] + bi);
                *(h4*)(C + (size_t)bb * ((size_t)Cc * Mm) + (size_t)col * Mm + ml) = st;
            }
        }
    } else if (EPI == 2) {     // gate: g = dec*(1+tanh(acc)), f16
        _Float16* C = (_Float16*)Cout + (size_t)b * sC;
        const float* Dg = aux + (size_t)b * sAux;
        #pragma unroll
        for (int i = 0; i < NI; ++i)
            #pragma unroll
            for (int j = 0; j < 4; ++j)
                #pragma unroll
                for (int r = 0; r < 4; ++r) {
                    const int row = crow0 + i * 16 + r;
                    const int col = ccol0 + j * 16;
                    const float a = acc[i][j][r];
                    const float t = 1.f - 2.f / (__expf(2.f * a) + 1.f);
                    const float g = Dg[(size_t)row * ldaux + col] * (1.f + t);
                    C[(size_t)row * ldc + col] = (_Float16)g;
                }
    } else if (EPI == 3) {     // relu(acc+bias), f16
        _Float16* C = (_Float16*)Cout;
        #pragma unroll
        for (int i = 0; i < NI; ++i)
            #pragma unroll
            for (int j = 0; j < 4; ++j) {
                const int col = ccol0 + j * 16;
                const float bi = aux[col];
                #pragma unroll
                for (int r = 0; r < 4; ++r) {
                    const int row = crow0 + i * 16 + r;
                    C[(size_t)row * ldc + col] = (_Float16)fmaxf(acc[i][j][r] + bi, 0.f);
                }
            }
    } else {                   // EPI 4: acc+bias, fp32 out
        float* C = (float*)Cout;
        #pragma unroll
        for (int i = 0; i < NI; ++i)
            #pragma unroll
            for (int j = 0; j < 4; ++j) {
                const int col = ccol0 + j * 16;
                const float bi = aux[col];
                #pragma unroll
                for (int r = 0; r < 4; ++r) {
                    const int row = crow0 + i * 16 + r;
                    C[(size_t)row * ldc + col] = acc[i][j][r] + bi;
                }
            }
    }
}

// ---------------------------------------------------------------------------
// Masked softmax over fp32 S row; writes P as f16 IN PLACE (lower 4KB of the
// row's 8KB slot). All reads complete before the stores -> safe.
// ---------------------------------------------------------------------------
__global__ __launch_bounds__(256) void softmax_kernel(float* __restrict__ S)
{
    float* p = S + (size_t)blockIdx.x * Mm;
    const int tid = threadIdx.x;
    const int wv = tid >> 6, ln = tid & 63;

    float4 a = *(const float4*)(p + tid * 4);
    float4 c = *(const float4*)(p + 1024 + tid * 4);

    float mx = fmaxf(fmaxf(fmaxf(a.x, a.y), fmaxf(a.z, a.w)),
                     fmaxf(fmaxf(c.x, c.y), fmaxf(c.z, c.w)));
    #pragma unroll
    for (int off = 32; off >= 1; off >>= 1)
        mx = fmaxf(mx, __shfl_xor(mx, off, 64));

    __shared__ float sm[4], ss[4];
    if (ln == 0) sm[wv] = mx;
    __syncthreads();
    mx = fmaxf(fmaxf(sm[0], sm[1]), fmaxf(sm[2], sm[3]));

    float e[8];
    e[0] = __expf(a.x - mx); e[1] = __expf(a.y - mx);
    e[2] = __expf(a.z - mx); e[3] = __expf(a.w - mx);
    e[4] = __expf(c.x - mx); e[5] = __expf(c.y - mx);
    e[6] = __expf(c.z - mx); e[7] = __expf(c.w - mx);
    float s = e[0]+e[1]+e[2]+e[3]+e[4]+e[5]+e[6]+e[7];
    #pragma unroll
    for (int off = 32; off >= 1; off >>= 1)
        s += __shfl_xor(s, off, 64);
    if (ln == 0) ss[wv] = s;
    __syncthreads();
    s = ss[0] + ss[1] + ss[2] + ss[3];

    const float inv = 1.0f / s;
    h4 o1, o2;
    o1[0] = (a.x == 0.f) ? (_Float16)0.f : (_Float16)(e[0] * inv);
    o1[1] = (a.y == 0.f) ? (_Float16)0.f : (_Float16)(e[1] * inv);
    o1[2] = (a.z == 0.f) ? (_Float16)0.f : (_Float16)(e[2] * inv);
    o1[3] = (a.w == 0.f) ? (_Float16)0.f : (_Float16)(e[3] * inv);
    o2[0] = (c.x == 0.f) ? (_Float16)0.f : (_Float16)(e[4] * inv);
    o2[1] = (c.y == 0.f) ? (_Float16)0.f : (_Float16)(e[5] * inv);
    o2[2] = (c.z == 0.f) ? (_Float16)0.f : (_Float16)(e[6] * inv);
    o2[3] = (c.w == 0.f) ? (_Float16)0.f : (_Float16)(e[7] * inv);
    _Float16* P = (_Float16*)p;
    *(h4*)(P + tid * 4) = o1;
    *(h4*)(P + 1024 + tid * 4) = o2;
}

// fp32 -> f16, vectorized x4. grid*256*4 == element count.
__global__ __launch_bounds__(256) void sconv(const float* __restrict__ x,
                                             _Float16* __restrict__ o)
{
    const size_t i = (size_t)blockIdx.x * 256 + threadIdx.x;
    f4 v = ((const f4*)x)[i];
    h4 hh;
    #pragma unroll
    for (int k = 0; k < 4; ++k) hh[k] = (_Float16)v[k];
    ((h4*)o)[i] = hh;
}

// W [512,512] fp32 -> Wt [512,512] f16 transposed (Wt[n][k] = W[k][n]).
__global__ __launch_bounds__(256) void wconv(const float* s0, const float* s1, const float* s2,
                                             _Float16* d0, _Float16* d1, _Float16* d2)
{
    const float* Sm = blockIdx.z == 0 ? s0 : blockIdx.z == 1 ? s1 : s2;
    _Float16* D = blockIdx.z == 0 ? d0 : blockIdx.z == 1 ? d1 : d2;
    __shared__ float t[32][33];
    const int x = threadIdx.x & 31, y = threadIdx.x >> 5;
    const int gx = blockIdx.x * 32, gy = blockIdx.y * 32;
    #pragma unroll
    for (int yy = y; yy < 32; yy += 8)
        t[yy][x] = Sm[(size_t)(gy + yy) * 512 + gx + x];
    __syncthreads();
    #pragma unroll
    for (int yy = y; yy < 32; yy += 8)
        D[(size_t)(gx + yy) * 512 + gy + x] = (_Float16)t[x][yy];
}

// ---------------------------------------------------------------------------
// ws budget: 160 MiB (proven). d_out doubles as scratch.
//   ws [0,128MiB)  : S fp32 (rows 8KB). P f16 in-place (lower 4KB halves).
//                    g f16 -> upper 4KB halves (PV). h f16 -> lower halves
//                    (fc1, after P dead). No cross-row reads of upper halves.
//   ws [128,144MiB): dec_h f16 (16MB); after score: Wvt/W1t/W2t (1.5MB).
//   ws [144,160MiB): vT f16 (16MB).
//   d_out [0,16MiB): enc_h f16; dead before fc2 writes.
// ---------------------------------------------------------------------------
extern "C" void kernel_launch(void* const* d_in, const int* in_sizes, int n_in,
                              void* d_out, int out_size, void* d_ws, size_t ws_size,
                              hipStream_t stream)
{
    const float* dec   = (const float*)d_in[0];
    const float* enc   = (const float*)d_in[1];
    const float* trans = (const float*)d_in[2];
    const float* Wv = (const float*)d_in[3];
    const float* bv = (const float*)d_in[4];
    const float* W1 = (const float*)d_in[5];
    const float* b1 = (const float*)d_in[6];
    const float* W2 = (const float*)d_in[7];
    const float* b2 = (const float*)d_in[8];

    char* ws = (char*)d_ws;
    float*     S     = (float*)ws;                  // 128 MiB
    _Float16*  P     = (_Float16*)ws;               // row stride 4096 halves
    _Float16*  g     = P + 2048;                    // upper halves, ld 4096
    _Float16*  h     = P;                           // lower halves, ld 4096
    _Float16*  dec_h = (_Float16*)(ws + 134217728); // [128,144) MiB
    _Float16*  Wvt   = dec_h;                       // post-score aliases
    _Float16*  W1t   = dec_h + 262144;
    _Float16*  W2t   = dec_h + 524288;
    _Float16*  vT    = (_Float16*)(ws + 150994944); // [144,160) MiB
    _Float16*  enc_h = (_Float16*)d_out;            // d_out as scratch

    sconv<<<dim3(8192), 256, 0, stream>>>(dec, dec_h);
    sconv<<<dim3(8192), 256, 0, stream>>>(enc, enc_h);

    // S = (dec @ enc^T) * mask   (f16 MFMA, fp32 out)
    gemm_mfma<0, 128><<<dim3(16, 16, 8), 256, 0, stream>>>(
        dec_h, (long)Nn * Cc, 512,
        enc_h, (long)Mm * Cc, 512,
        trans, (long)Nn * Mm, 2048, S, (long)Nn * Mm, 2048, 512);

    // masked softmax, P f16 in place (row stride 4096 halves)
    softmax_kernel<<<dim3(Bb * Nn), 256, 0, stream>>>(S);

    // weights f16-transposed into dec_h region (dead after score)
    wconv<<<dim3(16, 16, 3), 256, 0, stream>>>(Wv, W1, W2, Wvt, W1t, W2t);

    // v^T = (enc @ Wv + bv)^T  [B][C][M] f16
    gemm_mfma<1, 64><<<dim3(8, 128, 1), 256, 0, stream>>>(
        enc_h, 0, 512, Wvt, 0, 512, bv, 0, 0, vT, 0, 0, 512);

    // g = dec * (1 + tanh(P @ v))   f16 -> upper halves of S rows
    gemm_mfma<2, 64><<<dim3(8, 16, 8), 256, 0, stream>>>(
        P, (long)Nn * 4096, 4096,
        vT, (long)Cc * Mm, 2048,
        dec, (long)Nn * Cc, 512, g, (long)Nn * 4096, 4096, 2048);

    // h = relu(g @ W1 + b1)   f16 -> lower halves (P dead)
    gemm_mfma<3, 64><<<dim3(8, 128, 1), 256, 0, stream>>>(
        g, 0, 4096, W1t, 0, 512, b1, 0, 0, h, 0, 4096, 512);

    // out = h @ W2 + b2   fp32 (overwrites enc_h scratch)
    gemm_mfma<4, 64><<<dim3(8, 128, 1), 256, 0, stream>>>(
        h, 0, 4096, W2t, 0, 512, b2, 0, 0, d_out, 0, 512, 512);
}

// Round 6
// 466.787 us; speedup vs baseline: 3.0794x; 1.1924x over previous
//
#include <hip/hip_runtime.h>
#include <math.h>

#define Bb 8
#define Nn 2048
#define Mm 2048
#define Cc 512

typedef __attribute__((ext_vector_type(8))) _Float16 hfrag;  // 8 f16 = 4 VGPRs
typedef __attribute__((ext_vector_type(4))) float f4;        // MFMA acc
typedef __attribute__((ext_vector_type(4))) _Float16 h4;

__device__ __forceinline__ void gld16(const void* g, void* l) {
    __builtin_amdgcn_global_load_lds(
        (const __attribute__((address_space(1))) void*)g,
        (__attribute__((address_space(3))) void*)l, 16, 0, 0);
}

// ---------------------------------------------------------------------------
// MFMA GEMM (f16 in, fp32 acc), 128xBN tile, BK=32, 256 threads.
//   BN=128: 4 waves 2x2, each 64x64 (acc 4x4).
//   BN=64 : 4 waves row-stacked, each 32x64 (acc 2x4).
// A [rows,K] f16 row-major; Bt [cols,K] f16 row-major (pre-transposed).
// SWZ block swizzles (1-D launch):
//   0: plain 3-D grid.
//   1: bz=id&7 (batch pinned to XCD), bx=(id>>3)%GX, by=(id>>3)/GX —
//      same-strip col-blocks have ids Δ8 -> same XCD, concurrent -> L2 share.
//   2: bz=0, bx=(id>>3)%GX, by=(id&7)+8*((id>>3)/GX) — strip-grouping for
//      the batchless 512-wide GEMMs.
// EPI: 0=score+softmax-phase1 (mask, e=exp(s-m_t) f16 out + (m_t,l_t) partials)
//      1=vT (bias, f16 transposed out)  2=PV: A-frags scaled by alpha(row,t),
//        gate epilogue dec_h*(1+tanh) f16  3=relu+bias f16  4=bias fp32 out
// ---------------------------------------------------------------------------
template<int EPI, int BN, int SWZ>
__global__ __launch_bounds__(256) void gemm_mfma(
    const _Float16* __restrict__ Ah, long sA, int lda,
    const _Float16* __restrict__ Bh, long sB, int ldb,
    const float* __restrict__ aux, long sAux, int ldaux,     // mask / f32 bias
    const _Float16* __restrict__ aux2,                       // EPI2: dec_h (ld=ldaux)
    float* __restrict__ mlal,          // EPI0: (m,l) out; EPI2: alpha in
    void* __restrict__ Cout, long sC, int ldc, int K, int GX)
{
    constexpr int NI = (BN == 128) ? 4 : 2;
    constexpr int NQ = (512 + BN * 4) / 256;

    __shared__ _Float16 As[128 * 32];
    __shared__ _Float16 Bs[BN * 32];

    int bx, by, bz;
    if (SWZ == 1) {
        const int id = blockIdx.x;
        bz = id & 7; bx = (id >> 3) % GX; by = (id >> 3) / GX;
    } else if (SWZ == 2) {
        const int id = blockIdx.x;
        bz = 0; bx = (id >> 3) % GX; by = (id & 7) + 8 * ((id >> 3) / GX);
    } else {
        bx = blockIdx.x; by = blockIdx.y; bz = blockIdx.z;
    }

    const _Float16* A0 = Ah + (size_t)bz * sA;
    const _Float16* B0 = Bh + (size_t)bz * sB;

    const int tid  = threadIdx.x;
    const int wv   = tid >> 6;
    const int ln   = tid & 63;
    const int wx   = (BN == 128) ? (wv & 1) : 0;
    const int wy   = (BN == 128) ? (wv >> 1) : wv;
    const int lcol = ln & 15, quad = ln >> 4;
    const int row0w = wy * (NI * 16);
    const int col0w = wx * 64;

    const int rowBase = by * 128;
    const int colBase = bx * BN;

    f4 acc[NI][4];
    const f4 z4 = {0.f, 0.f, 0.f, 0.f};
    #pragma unroll
    for (int i = 0; i < NI; ++i)
        #pragma unroll
        for (int j = 0; j < 4; ++j) acc[i][j] = z4;

    // A-frag global rows (A-layout: m = lane&15) — for EPI2 alpha lookup
    const float* alb = (EPI == 2) ? (mlal + (size_t)bz * (2048 * 32)) : nullptr;

    for (int k0 = 0; k0 < K; k0 += 32) {
        __syncthreads();
        #pragma unroll
        for (int q = 0; q < NQ; ++q) {
            const int c0 = q * 256 + wv * 64;
            const int c  = c0 + ln;
            if (c0 < 512) {
                const int r  = c >> 2;
                const int ko = (c & 3) * 8;
                gld16(A0 + (size_t)(rowBase + r) * lda + k0 + ko, &As[c0 * 8]);
            } else {
                const int cb = c - 512;
                const int r  = cb >> 2;
                const int ko = (cb & 3) * 8;
                gld16(B0 + (size_t)(colBase + r) * ldb + k0 + ko, &Bs[(c0 - 512) * 8]);
            }
        }
        __syncthreads();

        hfrag af[NI], bf_[4];
        const int aoff = quad * 8;
        #pragma unroll
        for (int i = 0; i < NI; ++i)
            af[i]  = *(const hfrag*)&As[(row0w + i * 16 + lcol) * 32 + aoff];
        #pragma unroll
        for (int j = 0; j < 4; ++j)
            bf_[j] = *(const hfrag*)&Bs[(col0w + j * 16 + lcol) * 32 + aoff];

        if (EPI == 2) {        // scale A-frags by alpha(row, 64-col m-tile)
            const int t = k0 >> 6;
            #pragma unroll
            for (int i = 0; i < NI; ++i) {
                const int ar = rowBase + row0w + i * 16 + lcol;
                const _Float16 s = (_Float16)alb[(size_t)ar * 32 + t];
                af[i] = af[i] * s;
            }
        }

        #pragma unroll
        for (int i = 0; i < NI; ++i)
            #pragma unroll
            for (int j = 0; j < 4; ++j)
                acc[i][j] = __builtin_amdgcn_mfma_f32_16x16x32_f16(af[i], bf_[j], acc[i][j], 0, 0, 0);
    }

    // C/D layout: col = lane&15, row = quad*4 + reg
    const int crow0 = rowBase + row0w + quad * 4;
    const int ccol0 = colBase + col0w + lcol;

    if (EPI == 0) {  // score + softmax phase 1 (BN=128 only)
        _Float16* E = (_Float16*)Cout + (size_t)bz * sC;
        const float* Mk = aux + (size_t)bz * sAux;
        // s = score * mask (in place)
        #pragma unroll
        for (int i = 0; i < NI; ++i)
            #pragma unroll
            for (int j = 0; j < 4; ++j)
                #pragma unroll
                for (int r = 0; r < 4; ++r) {
                    const int row = crow0 + i * 16 + r;
                    const int col = ccol0 + j * 16;
                    acc[i][j][r] *= Mk[(size_t)row * ldaux + col];
                }
        const int t = bx * 2 + wx;          // 64-col tile index
        #pragma unroll
        for (int i = 0; i < NI; ++i) {
            #pragma unroll
            for (int r = 0; r < 4; ++r) {
                // row-local max over this wave's 64 cols (incl. masked zeros)
                float m0 = fmaxf(fmaxf(acc[i][0][r], acc[i][1][r]),
                                 fmaxf(acc[i][2][r], acc[i][3][r]));
                #pragma unroll
                for (int off = 1; off <= 8; off <<= 1)
                    m0 = fmaxf(m0, __shfl_xor(m0, off, 64));
                // e + row-local sum (masked contribute exp(0-m0))
                float l0 = 0.f;
                const int row = crow0 + i * 16 + r;
                #pragma unroll
                for (int j = 0; j < 4; ++j) {
                    const float s = acc[i][j][r];
                    const float e = __expf(s - m0);
                    l0 += e;
                    E[(size_t)row * ldc + (ccol0 + j * 16)] =
                        (s == 0.f) ? (_Float16)0.f : (_Float16)e;
                }
                #pragma unroll
                for (int off = 1; off <= 8; off <<= 1)
                    l0 += __shfl_xor(l0, off, 64);
                if ((ln & 15) == 0) {
                    float2 p; p.x = m0; p.y = l0;
                    ((float2*)mlal)[((size_t)bz * 2048 + row) * 32 + t] = p;
                }
            }
        }
    } else if (EPI == 1) {     // v^T: f16, vT[b][c][m] = acc + bias[c]
        _Float16* C = (_Float16*)Cout;
        #pragma unroll
        for (int j = 0; j < 4; ++j) {
            const int col = ccol0 + j * 16;
            const float bi = aux[col];
            #pragma unroll
            for (int i = 0; i < NI; ++i) {
                const int rowb = crow0 + i * 16;     // flattened b*M + m
                const int bb = rowb >> 11, ml = rowb & 2047;
                h4 st;
                #pragma unroll
                for (int r = 0; r < 4; ++r) st[r] = (_Float16)(acc[i][j][r] + bi);
                *(h4*)(C + (size_t)bb * ((size_t)Cc * Mm) + (size_t)col * Mm + ml) = st;
            }
        }
    } else if (EPI == 2) {     // gate: g = dec_h*(1+tanh(acc)), f16
        _Float16* C = (_Float16*)Cout + (size_t)bz * sC;
        const _Float16* Dg = aux2 + (size_t)bz * sC;
        #pragma unroll
        for (int i = 0; i < NI; ++i)
            #pragma unroll
            for (int j = 0; j < 4; ++j)
                #pragma unroll
                for (int r = 0; r < 4; ++r) {
                    const int row = crow0 + i * 16 + r;
                    const int col = ccol0 + j * 16;
                    const float a = acc[i][j][r];
                    const float th = 1.f - 2.f / (__expf(2.f * a) + 1.f);
                    const float g = (float)Dg[(size_t)row * ldaux + col] * (1.f + th);
                    C[(size_t)row * ldc + col] = (_Float16)g;
                }
    } else if (EPI == 3) {     // relu(acc+bias), f16
        _Float16* C = (_Float16*)Cout;
        #pragma unroll
        for (int i = 0; i < NI; ++i)
            #pragma unroll
            for (int j = 0; j < 4; ++j) {
                const int col = ccol0 + j * 16;
                const float bi = aux[col];
                #pragma unroll
                for (int r = 0; r < 4; ++r) {
                    const int row = crow0 + i * 16 + r;
                    C[(size_t)row * ldc + col] = (_Float16)fmaxf(acc[i][j][r] + bi, 0.f);
                }
            }
    } else {                   // EPI 4: acc+bias, fp32 out
        float* C = (float*)Cout;
        #pragma unroll
        for (int i = 0; i < NI; ++i)
            #pragma unroll
            for (int j = 0; j < 4; ++j) {
                const int col = ccol0 + j * 16;
                const float bi = aux[col];
                #pragma unroll
                for (int r = 0; r < 4; ++r) {
                    const int row = crow0 + i * 16 + r;
                    C[(size_t)row * ldc + col] = acc[i][j][r] + bi;
                }
            }
    }
}

// ---------------------------------------------------------------------------
// Combine softmax partials: per row, m = max_t m_t, l = sum_t l_t*exp(m_t-m),
// alpha(row,t) = exp(m_t-m)/l.  One thread per row, 64-thread blocks.
// ---------------------------------------------------------------------------
__global__ __launch_bounds__(64) void combine_kernel(
    const float* __restrict__ mlq, float* __restrict__ alpha)
{
    const int row = blockIdx.x * 64 + threadIdx.x;   // 0..16383
    const float2* ml = (const float2*)mlq + (size_t)row * 32;
    float mt[32], lt[32];
    float m = -1e30f;
    #pragma unroll
    for (int t = 0; t < 32; ++t) {
        float2 p = ml[t];
        mt[t] = p.x; lt[t] = p.y;
        m = fmaxf(m, p.x);
    }
    float et[32], l = 0.f;
    #pragma unroll
    for (int t = 0; t < 32; ++t) {
        et[t] = __expf(mt[t] - m);
        l += lt[t] * et[t];
    }
    const float inv = 1.f / l;
    float* ap = alpha + (size_t)row * 32;
    #pragma unroll
    for (int t = 0; t < 32; ++t) ap[t] = et[t] * inv;
}

// fp32 -> f16, vectorized x4. grid*256*4 == element count.
__global__ __launch_bounds__(256) void sconv(const float* __restrict__ x,
                                             _Float16* __restrict__ o)
{
    const size_t i = (size_t)blockIdx.x * 256 + threadIdx.x;
    f4 v = ((const f4*)x)[i];
    h4 hh;
    #pragma unroll
    for (int k = 0; k < 4; ++k) hh[k] = (_Float16)v[k];
    ((h4*)o)[i] = hh;
}

// W [512,512] fp32 -> Wt [512,512] f16 transposed (Wt[n][k] = W[k][n]).
__global__ __launch_bounds__(256) void wconv(const float* s0, const float* s1, const float* s2,
                                             _Float16* d0, _Float16* d1, _Float16* d2)
{
    const float* Sm = blockIdx.z == 0 ? s0 : blockIdx.z == 1 ? s1 : s2;
    _Float16* D = blockIdx.z == 0 ? d0 : blockIdx.z == 1 ? d1 : d2;
    __shared__ float t[32][33];
    const int x = threadIdx.x & 31, y = threadIdx.x >> 5;
    const int gx = blockIdx.x * 32, gy = blockIdx.y * 32;
    #pragma unroll
    for (int yy = y; yy < 32; yy += 8)
        t[yy][x] = Sm[(size_t)(gy + yy) * 512 + gx + x];
    __syncthreads();
    #pragma unroll
    for (int yy = y; yy < 32; yy += 8)
        D[(size_t)(gx + yy) * 512 + gy + x] = (_Float16)t[x][yy];
}

// ---------------------------------------------------------------------------
// ws layout (142.6 MiB used, within the 160 MiB proven budget):
//   e    [0x0000000, 0x4000000)  8x2048x2048 f16  (exp(s-m_t), masked=0)
//   mlq  [0x4000000, 0x4400000)  (m_t,l_t) float2 per (row, 64-col tile)
//   alpha[0x4400000, 0x4600000)  fp32 per (row, tile)
//   dec_h[0x4600000, 0x5600000)  f16
//   Wvt/W1t/W2t [0x5600000, +3*512KB)
//   vT   [0x5800000, 0x6800000)  f16 [B][C][M]
//   g    [0x6800000, 0x7800000)  f16 dense ld 512
//   h    [0x7800000, 0x8800000)  f16 dense ld 512
//   enc_h in d_out[0,16.8MB) (dead until fc2 writes).
// ---------------------------------------------------------------------------
extern "C" void kernel_launch(void* const* d_in, const int* in_sizes, int n_in,
                              void* d_out, int out_size, void* d_ws, size_t ws_size,
                              hipStream_t stream)
{
    const float* dec   = (const float*)d_in[0];
    const float* enc   = (const float*)d_in[1];
    const float* trans = (const float*)d_in[2];
    const float* Wv = (const float*)d_in[3];
    const float* bv = (const float*)d_in[4];
    const float* W1 = (const float*)d_in[5];
    const float* b1 = (const float*)d_in[6];
    const float* W2 = (const float*)d_in[7];
    const float* b2 = (const float*)d_in[8];

    char* ws = (char*)d_ws;
    _Float16* e     = (_Float16*)ws;
    float*    mlq   = (float*)(ws + 0x4000000);
    float*    alpha = (float*)(ws + 0x4400000);
    _Float16* dec_h = (_Float16*)(ws + 0x4600000);
    _Float16* Wvt   = (_Float16*)(ws + 0x5600000);
    _Float16* W1t   = Wvt + 262144;
    _Float16* W2t   = Wvt + 524288;
    _Float16* vT    = (_Float16*)(ws + 0x5800000);
    _Float16* g     = (_Float16*)(ws + 0x6800000);
    _Float16* h     = (_Float16*)(ws + 0x7800000);
    _Float16* enc_h = (_Float16*)d_out;

    sconv<<<dim3(8192), 256, 0, stream>>>(dec, dec_h);
    sconv<<<dim3(8192), 256, 0, stream>>>(enc, enc_h);
    wconv<<<dim3(16, 16, 3), 256, 0, stream>>>(Wv, W1, W2, Wvt, W1t, W2t);

    // e = exp(dec@enc^T * mask - m_t), partials (m_t,l_t)  [SWZ1, GX=16]
    gemm_mfma<0, 128, 1><<<dim3(2048), 256, 0, stream>>>(
        dec_h, (long)Nn * Cc, 512,
        enc_h, (long)Mm * Cc, 512,
        trans, (long)Nn * Mm, 2048, nullptr, mlq,
        e, (long)Nn * Mm, 2048, 512, 16);

    // per-row combine -> alpha
    combine_kernel<<<dim3(256), 64, 0, stream>>>(mlq, alpha);

    // v^T = (enc @ Wv + bv)^T  [B][C][M] f16   [SWZ2, GX=8]
    gemm_mfma<1, 64, 2><<<dim3(1024), 256, 0, stream>>>(
        enc_h, 0, 512, Wvt, 0, 512, bv, 0, 0, nullptr, nullptr,
        vT, 0, 0, 512, 8);

    // g = dec_h * (1 + tanh( (alpha·e) @ v ))   [SWZ1, GX=4]
    gemm_mfma<2, 128, 1><<<dim3(512), 256, 0, stream>>>(
        e, (long)Nn * Mm, 2048,
        vT, (long)Cc * Mm, 2048,
        nullptr, 0, 512, dec_h, alpha,
        g, (long)Nn * Cc, 512, 2048, 4);

    // h = relu(g @ W1 + b1)   [SWZ2, GX=8]
    gemm_mfma<3, 64, 2><<<dim3(1024), 256, 0, stream>>>(
        g, 0, 512, W1t, 0, 512, b1, 0, 0, nullptr, nullptr,
        h, 0, 512, 512, 8);

    // out = h @ W2 + b2  fp32   [SWZ2, GX=8]
    gemm_mfma<4, 64, 2><<<dim3(1024), 256, 0, stream>>>(
        h, 0, 512, W2t, 0, 512, b2, 0, 0, nullptr, nullptr,
        d_out, 0, 512, 512, 8);
}

// Round 7
// 460.095 us; speedup vs baseline: 3.1242x; 1.0145x over previous
//
#include <hip/hip_runtime.h>
#include <math.h>

#define Bb 8
#define Nn 2048
#define Mm 2048
#define Cc 512

typedef __attribute__((ext_vector_type(8))) _Float16 hfrag;  // 8 f16 = 4 VGPRs
typedef __attribute__((ext_vector_type(4))) float f4;        // MFMA acc
typedef __attribute__((ext_vector_type(4))) _Float16 h4;

__device__ __forceinline__ void gld16(const void* g, void* l) {
    __builtin_amdgcn_global_load_lds(
        (const __attribute__((address_space(1))) void*)g,
        (__attribute__((address_space(3))) void*)l, 16, 0, 0);
}

// ---------------------------------------------------------------------------
// MFMA GEMM (f16 in, fp32 acc), 128xBN tile, BK=32, 256 threads.
// C[r][c] = sum_k A[r][k]*Bt[c][k];  A,Bt k-contiguous.
// ALL epilogues store C TRANSPOSED: per (i,j) frag the 4 regs are 4
// consecutive rows -> contiguous 8B/16B stores at [col][row].
//   BN=128: 4 waves 2x2, each 64x64 (acc 4x4).
//   BN=64 : 4 waves row-stacked, each 32x64 (acc 2x4).
// SWZ: 0 plain 2-D (bz=0); 1: bz=id&7 (batch->XCD), bx=(id>>3)%GX, by=/GX.
//      2: bz=0, bx=(id>>3)%GX, by=(id&7)+8*((id>>3)/GX).
// EPI 0: score^T + softmax phase1. A=enc(rows=m), B=dec(cols=n).
//        acc=score[n][m]; *mask[n][m] (f4 along m); per-(n,t) m0,l0 (2 shfl);
//        e[n][m]=exp(s-m0) f16 h4-stores (masked->0); mlq[(bz,n,t)]=(m0,l0).
// EPI 1: vT. A=enc(rows=bm), Bt=Wv^T(cols=c). vT[b][c][m] = acc+bv[c], h4.
// EPI 2: PV+gate. A=vT(rows=c), B=e(cols=n), B-frags *= alpha(n,t).
//        g[n][c] = dec_h[n][c]*(1+tanh(acc)), h4 loads+stores.
// EPI 3: fc1. A=W1^T(rows=c2), B=g(cols=n). h[n][c2]=relu(acc+b1[c2]), h4.
// EPI 4: fc2. A=W2^T(rows=c3), B=h(cols=n). out[n][c3]=acc+b2[c3], f4 stores.
// ---------------------------------------------------------------------------
template<int EPI, int BN, int SWZ>
__global__ __launch_bounds__(256) void gemm_mfma(
    const _Float16* __restrict__ Ah, long sA, int lda,
    const _Float16* __restrict__ Bh, long sB, int ldb,
    const float* __restrict__ aux, long sAux, int ldaux,     // mask / f32 bias
    const _Float16* __restrict__ aux2,                       // EPI2: dec_h
    float* __restrict__ mlal,          // EPI0: (m,l) out; EPI2: alpha in
    void* __restrict__ Cout, long sC, int ldc, int K, int GX)
{
    constexpr int NI = (BN == 128) ? 4 : 2;
    constexpr int NQ = (512 + BN * 4) / 256;

    __shared__ _Float16 As[128 * 32];
    __shared__ _Float16 Bs[BN * 32];

    int bx, by, bz;
    if (SWZ == 1) {
        const int id = blockIdx.x;
        bz = id & 7; bx = (id >> 3) % GX; by = (id >> 3) / GX;
    } else if (SWZ == 2) {
        const int id = blockIdx.x;
        bz = 0; bx = (id >> 3) % GX; by = (id & 7) + 8 * ((id >> 3) / GX);
    } else {
        bx = blockIdx.x; by = blockIdx.y; bz = 0;
    }

    const _Float16* A0 = Ah + (size_t)bz * sA;
    const _Float16* B0 = Bh + (size_t)bz * sB;

    const int tid  = threadIdx.x;
    const int wv   = tid >> 6;
    const int ln   = tid & 63;
    const int wx   = (BN == 128) ? (wv & 1) : 0;
    const int wy   = (BN == 128) ? (wv >> 1) : wv;
    const int lcol = ln & 15, quad = ln >> 4;
    const int row0w = wy * (NI * 16);
    const int col0w = wx * 64;

    const int rowBase = by * 128;
    const int colBase = bx * BN;

    f4 acc[NI][4];
    const f4 z4 = {0.f, 0.f, 0.f, 0.f};
    #pragma unroll
    for (int i = 0; i < NI; ++i)
        #pragma unroll
        for (int j = 0; j < 4; ++j) acc[i][j] = z4;

    // EPI2: per-batch alpha base, cached per 64-k tile
    const float* alb = (EPI == 2) ? (mlal + (size_t)bz * (2048 * 32)) : nullptr;
    _Float16 als[4] = {(_Float16)0.f, (_Float16)0.f, (_Float16)0.f, (_Float16)0.f};

    for (int k0 = 0; k0 < K; k0 += 32) {
        __syncthreads();
        #pragma unroll
        for (int q = 0; q < NQ; ++q) {
            const int c0 = q * 256 + wv * 64;
            const int c  = c0 + ln;
            if (c0 < 512) {
                const int r  = c >> 2;
                const int ko = (c & 3) * 8;
                gld16(A0 + (size_t)(rowBase + r) * lda + k0 + ko, &As[c0 * 8]);
            } else {
                const int cb = c - 512;
                const int r  = cb >> 2;
                const int ko = (cb & 3) * 8;
                gld16(B0 + (size_t)(colBase + r) * ldb + k0 + ko, &Bs[(c0 - 512) * 8]);
            }
        }
        __syncthreads();

        hfrag af[NI], bf_[4];
        const int aoff = quad * 8;
        #pragma unroll
        for (int i = 0; i < NI; ++i)
            af[i]  = *(const hfrag*)&As[(row0w + i * 16 + lcol) * 32 + aoff];
        #pragma unroll
        for (int j = 0; j < 4; ++j)
            bf_[j] = *(const hfrag*)&Bs[(col0w + j * 16 + lcol) * 32 + aoff];

        if (EPI == 2) {        // alpha(n, t) on B-frags
            if ((k0 & 63) == 0) {
                const int t = k0 >> 6;
                #pragma unroll
                for (int j = 0; j < 4; ++j) {
                    const int n = colBase + col0w + j * 16 + lcol;
                    als[j] = (_Float16)alb[(size_t)n * 32 + t];
                }
            }
            #pragma unroll
            for (int j = 0; j < 4; ++j) bf_[j] = bf_[j] * als[j];
        }

        #pragma unroll
        for (int i = 0; i < NI; ++i)
            #pragma unroll
            for (int j = 0; j < 4; ++j)
                acc[i][j] = __builtin_amdgcn_mfma_f32_16x16x32_f16(af[i], bf_[j], acc[i][j], 0, 0, 0);
    }

    // C/D layout: col = lane&15, row = quad*4 + reg   [verified m89/m91]
    const int crow0 = rowBase + row0w + quad * 4;
    const int ccol0 = colBase + col0w + lcol;

    if (EPI == 0) {  // score^T + softmax phase 1 (BN=128): rows=m, cols=n
        _Float16* E = (_Float16*)Cout + (size_t)bz * sC;   // e[n][m], ld=ldc
        const float* Mk = aux + (size_t)bz * sAux;          // mask[n][m]
        #pragma unroll
        for (int i = 0; i < NI; ++i) {
            const int m0r = crow0 + i * 16;
            #pragma unroll
            for (int j = 0; j < 4; ++j) {
                const int n = ccol0 + j * 16;
                const f4 mk = *(const f4*)(Mk + (size_t)n * ldaux + m0r);
                #pragma unroll
                for (int r = 0; r < 4; ++r) acc[i][j][r] *= mk[r];
            }
        }
        const int t = (rowBase + row0w) >> 6;      // 64-wide m-tile index
        #pragma unroll
        for (int j = 0; j < 4; ++j) {
            const int n = ccol0 + j * 16;
            float mx = acc[0][j][0];
            #pragma unroll
            for (int i = 0; i < NI; ++i)
                #pragma unroll
                for (int r = 0; r < 4; ++r) mx = fmaxf(mx, acc[i][j][r]);
            mx = fmaxf(mx, __shfl_xor(mx, 16, 64));
            mx = fmaxf(mx, __shfl_xor(mx, 32, 64));
            float l0 = 0.f;
            #pragma unroll
            for (int i = 0; i < NI; ++i) {
                h4 ev;
                #pragma unroll
                for (int r = 0; r < 4; ++r) {
                    const float s = acc[i][j][r];
                    const float e = __expf(s - mx);
                    l0 += e;
                    ev[r] = (s == 0.f) ? (_Float16)0.f : (_Float16)e;
                }
                *(h4*)(E + (size_t)n * ldc + crow0 + i * 16) = ev;
            }
            l0 += __shfl_xor(l0, 16, 64);
            l0 += __shfl_xor(l0, 32, 64);
            if (quad == 0) {
                float2 p; p.x = mx; p.y = l0;
                ((float2*)mlal)[((size_t)bz * 2048 + n) * 32 + t] = p;
            }
        }
    } else if (EPI == 1) {     // v^T: vT[b][c][m] = acc + bias[c], h4
        _Float16* C = (_Float16*)Cout;
        #pragma unroll
        for (int j = 0; j < 4; ++j) {
            const int col = ccol0 + j * 16;          // c index
            const float bi = aux[col];
            #pragma unroll
            for (int i = 0; i < NI; ++i) {
                const int rowb = crow0 + i * 16;     // flattened b*M + m
                const int bb = rowb >> 11, ml = rowb & 2047;
                h4 st;
                #pragma unroll
                for (int r = 0; r < 4; ++r) st[r] = (_Float16)(acc[i][j][r] + bi);
                *(h4*)(C + (size_t)bb * ((size_t)Cc * Mm) + (size_t)col * Mm + ml) = st;
            }
        }
    } else if (EPI == 2) {     // gate: g[n][c] = dec_h[n][c]*(1+tanh(acc))
        _Float16* C = (_Float16*)Cout + (size_t)bz * sC;
        const _Float16* Dg = aux2 + (size_t)bz * sC;
        #pragma unroll
        for (int i = 0; i < NI; ++i) {
            const int c0 = crow0 + i * 16;
            #pragma unroll
            for (int j = 0; j < 4; ++j) {
                const int n = ccol0 + j * 16;
                const h4 dv = *(const h4*)(Dg + (size_t)n * ldc + c0);
                h4 gv;
                #pragma unroll
                for (int r = 0; r < 4; ++r) {
                    const float a = acc[i][j][r];
                    const float th = 1.f - 2.f / (__expf(2.f * a) + 1.f);
                    gv[r] = (_Float16)((float)dv[r] * (1.f + th));
                }
                *(h4*)(C + (size_t)n * ldc + c0) = gv;
            }
        }
    } else if (EPI == 3) {     // fc1: h[n][c2] = relu(acc + b1[c2]), h4
        _Float16* C = (_Float16*)Cout;
        #pragma unroll
        for (int i = 0; i < NI; ++i) {
            const int c0 = crow0 + i * 16;
            const f4 bi = *(const f4*)(aux + c0);
            #pragma unroll
            for (int j = 0; j < 4; ++j) {
                const int n = ccol0 + j * 16;
                h4 hv;
                #pragma unroll
                for (int r = 0; r < 4; ++r)
                    hv[r] = (_Float16)fmaxf(acc[i][j][r] + bi[r], 0.f);
                *(h4*)(C + (size_t)n * ldc + c0) = hv;
            }
        }
    } else {                   // fc2: out[n][c3] = acc + b2[c3], f4 stores
        float* C = (float*)Cout;
        #pragma unroll
        for (int i = 0; i < NI; ++i) {
            const int c0 = crow0 + i * 16;
            const f4 bi = *(const f4*)(aux + c0);
            #pragma unroll
            for (int j = 0; j < 4; ++j) {
                const int n = ccol0 + j * 16;
                f4 ov;
                #pragma unroll
                for (int r = 0; r < 4; ++r) ov[r] = acc[i][j][r] + bi[r];
                *(f4*)(C + (size_t)n * ldc + c0) = ov;
            }
        }
    }
}

// ---------------------------------------------------------------------------
// Combine softmax partials: per row, m = max_t m_t, l = sum_t l_t*exp(m_t-m),
// alpha(row,t) = exp(m_t-m)/l.  One thread per row, 64-thread blocks.
// ---------------------------------------------------------------------------
__global__ __launch_bounds__(64) void combine_kernel(
    const float* __restrict__ mlq, float* __restrict__ alpha)
{
    const int row = blockIdx.x * 64 + threadIdx.x;   // 0..16383
    const float2* ml = (const float2*)mlq + (size_t)row * 32;
    float mt[32], lt[32];
    float m = -1e30f;
    #pragma unroll
    for (int t = 0; t < 32; ++t) {
        float2 p = ml[t];
        mt[t] = p.x; lt[t] = p.y;
        m = fmaxf(m, p.x);
    }
    float et[32], l = 0.f;
    #pragma unroll
    for (int t = 0; t < 32; ++t) {
        et[t] = __expf(mt[t] - m);
        l += lt[t] * et[t];
    }
    const float inv = 1.f / l;
    float* ap = alpha + (size_t)row * 32;
    #pragma unroll
    for (int t = 0; t < 32; ++t) ap[t] = et[t] * inv;
}

// fp32 -> f16, vectorized x4. grid*256*4 == element count.
__global__ __launch_bounds__(256) void sconv(const float* __restrict__ x,
                                             _Float16* __restrict__ o)
{
    const size_t i = (size_t)blockIdx.x * 256 + threadIdx.x;
    f4 v = ((const f4*)x)[i];
    h4 hh;
    #pragma unroll
    for (int k = 0; k < 4; ++k) hh[k] = (_Float16)v[k];
    ((h4*)o)[i] = hh;
}

// W [512,512] fp32 -> Wt [512,512] f16 transposed (Wt[n][k] = W[k][n]).
__global__ __launch_bounds__(256) void wconv(const float* s0, const float* s1, const float* s2,
                                             _Float16* d0, _Float16* d1, _Float16* d2)
{
    const float* Sm = blockIdx.z == 0 ? s0 : blockIdx.z == 1 ? s1 : s2;
    _Float16* D = blockIdx.z == 0 ? d0 : blockIdx.z == 1 ? d1 : d2;
    __shared__ float t[32][33];
    const int x = threadIdx.x & 31, y = threadIdx.x >> 5;
    const int gx = blockIdx.x * 32, gy = blockIdx.y * 32;
    #pragma unroll
    for (int yy = y; yy < 32; yy += 8)
        t[yy][x] = Sm[(size_t)(gy + yy) * 512 + gx + x];
    __syncthreads();
    #pragma unroll
    for (int yy = y; yy < 32; yy += 8)
        D[(size_t)(gx + yy) * 512 + gy + x] = (_Float16)t[x][yy];
}

// ---------------------------------------------------------------------------
// ws layout (same as R6, 142.6 MiB < 160 MiB proven):
//   e    [0x0000000, 0x4000000)  8x2048x2048 f16 e[n][m]
//   mlq  [0x4000000, 0x4400000)  (m_t,l_t) float2 per (row, m-tile)
//   alpha[0x4400000, 0x4600000)  fp32
//   dec_h[0x4600000, 0x5600000)  f16 [bn][c]
//   Wvt/W1t/W2t [0x5600000, +3*512KB)
//   vT   [0x5800000, 0x6800000)  f16 [b][c][m]
//   g    [0x6800000, 0x7800000)  f16 [bn][c]
//   h    [0x7800000, 0x8800000)  f16 [bn][c2]
//   enc_h in d_out (dead before fc2 writes).
// ---------------------------------------------------------------------------
extern "C" void kernel_launch(void* const* d_in, const int* in_sizes, int n_in,
                              void* d_out, int out_size, void* d_ws, size_t ws_size,
                              hipStream_t stream)
{
    const float* dec   = (const float*)d_in[0];
    const float* enc   = (const float*)d_in[1];
    const float* trans = (const float*)d_in[2];
    const float* Wv = (const float*)d_in[3];
    const float* bv = (const float*)d_in[4];
    const float* W1 = (const float*)d_in[5];
    const float* b1 = (const float*)d_in[6];
    const float* W2 = (const float*)d_in[7];
    const float* b2 = (const float*)d_in[8];

    char* ws = (char*)d_ws;
    _Float16* e     = (_Float16*)ws;
    float*    mlq   = (float*)(ws + 0x4000000);
    float*    alpha = (float*)(ws + 0x4400000);
    _Float16* dec_h = (_Float16*)(ws + 0x4600000);
    _Float16* Wvt   = (_Float16*)(ws + 0x5600000);
    _Float16* W1t   = Wvt + 262144;
    _Float16* W2t   = Wvt + 524288;
    _Float16* vT    = (_Float16*)(ws + 0x5800000);
    _Float16* g     = (_Float16*)(ws + 0x6800000);
    _Float16* h     = (_Float16*)(ws + 0x7800000);
    _Float16* enc_h = (_Float16*)d_out;

    sconv<<<dim3(8192), 256, 0, stream>>>(dec, dec_h);
    sconv<<<dim3(8192), 256, 0, stream>>>(enc, enc_h);
    wconv<<<dim3(16, 16, 3), 256, 0, stream>>>(Wv, W1, W2, Wvt, W1t, W2t);

    // e[n][m] = exp(mask*scores - m_t):  A=enc (rows=m), B=dec (cols=n)
    gemm_mfma<0, 128, 1><<<dim3(2048), 256, 0, stream>>>(
        enc_h, (long)Mm * Cc, 512,
        dec_h, (long)Nn * Cc, 512,
        trans, (long)Nn * Mm, 2048, nullptr, mlq,
        e, (long)Nn * Mm, 2048, 512, 16);

    // per-row combine -> alpha
    combine_kernel<<<dim3(256), 64, 0, stream>>>(mlq, alpha);

    // v^T = (enc @ Wv + bv)^T  [b][c][m]   [SWZ2, GX=8]
    gemm_mfma<1, 64, 2><<<dim3(1024), 256, 0, stream>>>(
        enc_h, 0, 512, Wvt, 0, 512, bv, 0, 0, nullptr, nullptr,
        vT, 0, 0, 512, 8);

    // g[n][c] = dec_h*(1+tanh((alpha.e) @ v)):  A=vT (rows=c), B=e (cols=n)
    gemm_mfma<2, 128, 1><<<dim3(512), 256, 0, stream>>>(
        vT, (long)Cc * Mm, 2048,
        e, (long)Nn * Mm, 2048,
        nullptr, 0, 512, dec_h, alpha,
        g, (long)Nn * Cc, 512, 2048, 16);

    // h[n][c2] = relu(g @ W1 + b1):  A=W1^T (rows=c2), B=g (cols=n)
    gemm_mfma<3, 64, 0><<<dim3(256, 4), 256, 0, stream>>>(
        W1t, 0, 512, g, 0, 512, b1, 0, 0, nullptr, nullptr,
        h, 0, 512, 512, 0);

    // out[n][c3] = h @ W2 + b2:  A=W2^T (rows=c3), B=h (cols=n), fp32
    gemm_mfma<4, 64, 0><<<dim3(256, 4), 256, 0, stream>>>(
        W2t, 0, 512, h, 0, 512, b2, 0, 0, nullptr, nullptr,
        d_out, 0, 512, 512, 0);
}